// Round 1
// baseline (1656.751 us; speedup 1.0000x reference)
//
#include <hip/hip_runtime.h>

#define N_NODES 100000
#define N_EDGES 1600000
#define N_GRAPHS 1000
#define D 128
#define LATENT 64
#define EPS 1e-5f
#define NB ((N_NODES + 255) / 256)   // 391
#define BM 128
#define LDP 132                       // padded LDS row (floats), 16B-aligned rows

// ---------------- CSR build ----------------

__global__ void hist_kernel(const int* __restrict__ dst, int* __restrict__ deg) {
    for (int e = blockIdx.x * blockDim.x + threadIdx.x; e < N_EDGES; e += gridDim.x * blockDim.x)
        atomicAdd(&deg[dst[e]], 1);
}

__global__ void scan_block_sum(const int* __restrict__ deg, int* __restrict__ bsum) {
    __shared__ int s[256];
    int t = threadIdx.x;
    int i = blockIdx.x * 256 + t;
    s[t] = (i < N_NODES) ? deg[i] : 0;
    __syncthreads();
    for (int off = 128; off > 0; off >>= 1) {
        if (t < off) s[t] += s[t + off];
        __syncthreads();
    }
    if (t == 0) bsum[blockIdx.x] = s[0];
}

__global__ void scan_top(const int* __restrict__ bsum, int* __restrict__ boff) {
    __shared__ int s[512];
    int t = threadIdx.x;
    int v = (t < NB) ? bsum[t] : 0;
    s[t] = v;
    __syncthreads();
    for (int off = 1; off < 512; off <<= 1) {
        int add = (t >= off) ? s[t - off] : 0;
        __syncthreads();
        s[t] += add;
        __syncthreads();
    }
    if (t < NB) boff[t] = s[t] - v;
}

__global__ void scan_apply(const int* __restrict__ deg, const int* __restrict__ boff,
                           int* __restrict__ offsets, int* __restrict__ cursor) {
    __shared__ int s[256];
    int t = threadIdx.x;
    int i = blockIdx.x * 256 + t;
    int v = (i < N_NODES) ? deg[i] : 0;
    s[t] = v;
    __syncthreads();
    for (int off = 1; off < 256; off <<= 1) {
        int add = (t >= off) ? s[t - off] : 0;
        __syncthreads();
        s[t] += add;
        __syncthreads();
    }
    int base = boff[blockIdx.x];
    if (i < N_NODES) {
        int ex = base + s[t] - v;
        offsets[i] = ex;
        cursor[i] = ex;
    }
    if (i == N_NODES - 1) offsets[N_NODES] = base + s[t];
}

__global__ void csr_fill(const int* __restrict__ src, const int* __restrict__ dst,
                         int* __restrict__ cursor, int* __restrict__ csr) {
    for (int e = blockIdx.x * blockDim.x + threadIdx.x; e < N_EDGES; e += gridDim.x * blockDim.x) {
        int d = dst[e];
        int p = atomicAdd(&cursor[d], 1);
        csr[p] = src[e];
    }
}

// ---------------- aggregation: agg = x + sum_{j->i} x_j ----------------

__global__ void agg_kernel(const float* __restrict__ x, const int* __restrict__ csr,
                           const int* __restrict__ offsets, float* __restrict__ agg) {
    int f = threadIdx.x & 127;
    int half = threadIdx.x >> 7;
    for (int pair = blockIdx.x; pair < N_NODES / 2; pair += gridDim.x) {
        int node = pair * 2 + half;
        int s = offsets[node], e = offsets[node + 1];
        float acc = x[(size_t)node * D + f];
        for (int p = s; p < e; ++p) {
            int j = csr[p];
            acc += x[(size_t)j * D + f];
        }
        agg[(size_t)node * D + f] = acc;
    }
}

// ---------------- GEMM1: H = leaky(A @ W + b), in-place over A; fused BN col stats ----------------
// 512 threads, 128-row tile, full K=128. Thread micro-tile: 4 rows x 8 cols
// (cols c0..c0+3 and c0+64..c0+67, c0 = (tid&15)*4 -> conflict-free LDS W reads).

__global__ __launch_bounds__(512, 1)
void gemm1_kernel(float* AH, const float* __restrict__ W, const float* __restrict__ bias,
                  float* __restrict__ colsum, float* __restrict__ colsq) {
    __shared__ float As[BM][LDP];
    __shared__ float Ws[D][LDP];
    __shared__ float csum[D], csq[D];
    int tid = threadIdx.x;
    int row0 = blockIdx.x * BM;
#pragma unroll
    for (int j = 0; j < 8; ++j) {
        int o = (j * 512 + tid) * 4;
        int k = o >> 7, c = o & 127;
        *(float4*)&Ws[k][c] = *(const float4*)&W[o];
        float4 a = make_float4(0.f, 0.f, 0.f, 0.f);
        if (row0 + k < N_NODES) a = *(const float4*)&AH[(size_t)(row0 + k) * D + c];
        *(float4*)&As[k][c] = a;
    }
    if (tid < D) { csum[tid] = 0.f; csq[tid] = 0.f; }
    __syncthreads();

    int c0 = (tid & 15) * 4;
    int r0 = (tid >> 4) * 4;
    float acc[4][8];
#pragma unroll
    for (int i = 0; i < 4; ++i)
#pragma unroll
        for (int j = 0; j < 8; ++j) acc[i][j] = 0.f;

    for (int k = 0; k < D; k += 4) {
        float a[4][4];
#pragma unroll
        for (int i = 0; i < 4; ++i) {
            float4 t = *(float4*)&As[r0 + i][k];
            a[i][0] = t.x; a[i][1] = t.y; a[i][2] = t.z; a[i][3] = t.w;
        }
#pragma unroll
        for (int kk = 0; kk < 4; ++kk) {
            float4 w0 = *(float4*)&Ws[k + kk][c0];
            float4 w1 = *(float4*)&Ws[k + kk][c0 + 64];
#pragma unroll
            for (int i = 0; i < 4; ++i) {
                float av = a[i][kk];
                acc[i][0] += av * w0.x; acc[i][1] += av * w0.y;
                acc[i][2] += av * w0.z; acc[i][3] += av * w0.w;
                acc[i][4] += av * w1.x; acc[i][5] += av * w1.y;
                acc[i][6] += av * w1.z; acc[i][7] += av * w1.w;
            }
        }
    }

    int cols[8];
#pragma unroll
    for (int j = 0; j < 8; ++j) cols[j] = c0 + (j >> 2) * 64 + (j & 3);
    float bs[8], ls[8], lq[8];
#pragma unroll
    for (int j = 0; j < 8; ++j) { bs[j] = bias[cols[j]]; ls[j] = 0.f; lq[j] = 0.f; }

#pragma unroll
    for (int i = 0; i < 4; ++i) {
        int gr = row0 + r0 + i;
        if (gr < N_NODES) {
            float v[8];
#pragma unroll
            for (int j = 0; j < 8; ++j) {
                float z = acc[i][j] + bs[j];
                z = (z >= 0.f) ? z : 0.2f * z;
                v[j] = z;
                ls[j] += z; lq[j] += z * z;
            }
            *(float4*)&AH[(size_t)gr * D + c0]      = make_float4(v[0], v[1], v[2], v[3]);
            *(float4*)&AH[(size_t)gr * D + c0 + 64] = make_float4(v[4], v[5], v[6], v[7]);
        }
    }
    // reduce lanes sharing same c0 within wave (lanes l, l+16, l+32, l+48)
#pragma unroll
    for (int j = 0; j < 8; ++j) {
        ls[j] += __shfl_down(ls[j], 32);
        ls[j] += __shfl_down(ls[j], 16);
        lq[j] += __shfl_down(lq[j], 32);
        lq[j] += __shfl_down(lq[j], 16);
    }
    if ((tid & 63) < 16) {
#pragma unroll
        for (int j = 0; j < 8; ++j) {
            atomicAdd(&csum[cols[j]], ls[j]);
            atomicAdd(&csq[cols[j]], lq[j]);
        }
    }
    __syncthreads();
    if (tid < D) {
        atomicAdd(&colsum[tid], csum[tid]);
        atomicAdd(&colsq[tid], csq[tid]);
    }
}

// ---------------- BN finalize ----------------

__global__ void bn_fin(const float* __restrict__ colsum, const float* __restrict__ colsq,
                       const float* __restrict__ g, const float* __restrict__ bt,
                       float* __restrict__ scale, float* __restrict__ shift, float inv_n) {
    int c = threadIdx.x;
    float m = colsum[c] * inv_n;
    float var = colsq[c] * inv_n - m * m;
    var = fmaxf(var, 0.f);
    float sc = g[c] * rsqrtf(var + EPS);
    scale[c] = sc;
    shift[c] = bt[c] - m * sc;
}

// ---------------- GEMM2: X = leaky(BN(H) @ W + b) + x_res ----------------

__global__ __launch_bounds__(512, 1)
void gemm2_kernel(const float* __restrict__ H, const float* __restrict__ W,
                  const float* __restrict__ bias, const float* __restrict__ scale,
                  const float* __restrict__ shift, const float* xres, float* xout) {
    __shared__ float As[BM][LDP];
    __shared__ float Ws[D][LDP];
    int tid = threadIdx.x;
    int row0 = blockIdx.x * BM;
#pragma unroll
    for (int j = 0; j < 8; ++j) {
        int o = (j * 512 + tid) * 4;
        int k = o >> 7, c = o & 127;
        *(float4*)&Ws[k][c] = *(const float4*)&W[o];
        float4 a = make_float4(0.f, 0.f, 0.f, 0.f);
        if (row0 + k < N_NODES) {
            a = *(const float4*)&H[(size_t)(row0 + k) * D + c];
            a.x = a.x * scale[c] + shift[c];
            a.y = a.y * scale[c + 1] + shift[c + 1];
            a.z = a.z * scale[c + 2] + shift[c + 2];
            a.w = a.w * scale[c + 3] + shift[c + 3];
        }
        *(float4*)&As[k][c] = a;
    }
    __syncthreads();

    int c0 = (tid & 15) * 4;
    int r0 = (tid >> 4) * 4;
    float acc[4][8];
#pragma unroll
    for (int i = 0; i < 4; ++i)
#pragma unroll
        for (int j = 0; j < 8; ++j) acc[i][j] = 0.f;

    for (int k = 0; k < D; k += 4) {
        float a[4][4];
#pragma unroll
        for (int i = 0; i < 4; ++i) {
            float4 t = *(float4*)&As[r0 + i][k];
            a[i][0] = t.x; a[i][1] = t.y; a[i][2] = t.z; a[i][3] = t.w;
        }
#pragma unroll
        for (int kk = 0; kk < 4; ++kk) {
            float4 w0 = *(float4*)&Ws[k + kk][c0];
            float4 w1 = *(float4*)&Ws[k + kk][c0 + 64];
#pragma unroll
            for (int i = 0; i < 4; ++i) {
                float av = a[i][kk];
                acc[i][0] += av * w0.x; acc[i][1] += av * w0.y;
                acc[i][2] += av * w0.z; acc[i][3] += av * w0.w;
                acc[i][4] += av * w1.x; acc[i][5] += av * w1.y;
                acc[i][6] += av * w1.z; acc[i][7] += av * w1.w;
            }
        }
    }

    int cols[8];
#pragma unroll
    for (int j = 0; j < 8; ++j) cols[j] = c0 + (j >> 2) * 64 + (j & 3);
    float bs[8];
#pragma unroll
    for (int j = 0; j < 8; ++j) bs[j] = bias[cols[j]];

#pragma unroll
    for (int i = 0; i < 4; ++i) {
        int gr = row0 + r0 + i;
        if (gr < N_NODES) {
            float4 xr0 = *(const float4*)&xres[(size_t)gr * D + c0];
            float4 xr1 = *(const float4*)&xres[(size_t)gr * D + c0 + 64];
            float v[8];
#pragma unroll
            for (int j = 0; j < 8; ++j) {
                float z = acc[i][j] + bs[j];
                v[j] = (z >= 0.f) ? z : 0.2f * z;
            }
            v[0] += xr0.x; v[1] += xr0.y; v[2] += xr0.z; v[3] += xr0.w;
            v[4] += xr1.x; v[5] += xr1.y; v[6] += xr1.z; v[7] += xr1.w;
            *(float4*)&xout[(size_t)gr * D + c0]      = make_float4(v[0], v[1], v[2], v[3]);
            *(float4*)&xout[(size_t)gr * D + c0 + 64] = make_float4(v[4], v[5], v[6], v[7]);
        }
    }
}

// ---------------- pooling + final BN + fc ----------------

__global__ void bounds_kernel(const int* __restrict__ batch, int* __restrict__ gs, int* __restrict__ ge) {
    for (int i = blockIdx.x * blockDim.x + threadIdx.x; i < N_NODES; i += gridDim.x * blockDim.x) {
        int b = batch[i];
        atomicMin(&gs[b], i);
        atomicMax(&ge[b], i + 1);
    }
}

__global__ void pool_kernel(const float* __restrict__ x, const int* __restrict__ gs,
                            const int* __restrict__ ge, float* __restrict__ pooled) {
    int g = blockIdx.x, f = threadIdx.x;
    int s = gs[g], e = ge[g];
    float acc = 0.f;
    for (int i = s; i < e; ++i) acc += x[(size_t)i * D + f];
    pooled[g * D + f] = acc;
}

__global__ void pooled_bn(const float* __restrict__ pooled, const float* __restrict__ g,
                          const float* __restrict__ b, float* __restrict__ pscale,
                          float* __restrict__ pshift) {
    int c = threadIdx.x;
    float s = 0.f, q = 0.f;
    for (int gi = 0; gi < N_GRAPHS; ++gi) {
        float v = pooled[gi * D + c];
        s += v; q += v * v;
    }
    float m = s / N_GRAPHS;
    float var = q / N_GRAPHS - m * m;
    var = fmaxf(var, 0.f);
    float sc = g[c] * rsqrtf(var + EPS);
    pscale[c] = sc;
    pshift[c] = b[c] - m * sc;
}

__global__ void out_kernel(const float* __restrict__ pooled, const float* __restrict__ pscale,
                           const float* __restrict__ pshift, const float* __restrict__ fcW,
                           const float* __restrict__ fcb, float* __restrict__ out) {
    int idx = blockIdx.x * blockDim.x + threadIdx.x;
    if (idx >= N_GRAPHS * LATENT) return;
    int g = idx >> 6, j = idx & 63;
    float acc = fcb[j];
    for (int c = 0; c < D; ++c) {
        float pv = pooled[g * D + c] * pscale[c] + pshift[c];
        acc += pv * fcW[c * LATENT + j];
    }
    out[idx] = acc;
}

// ---------------- launch ----------------

extern "C" void kernel_launch(void* const* d_in, const int* in_sizes, int n_in,
                              void* d_out, int out_size, void* d_ws, size_t ws_size,
                              hipStream_t stream) {
    const float* x_in = (const float*)d_in[0];
    const int* edges  = (const int*)d_in[1];
    const int* batch  = (const int*)d_in[2];
    const float* W1   = (const float*)d_in[3];
    const float* b1   = (const float*)d_in[4];
    const float* g1   = (const float*)d_in[5];
    const float* bt1  = (const float*)d_in[6];
    const float* W2   = (const float*)d_in[7];
    const float* b2   = (const float*)d_in[8];
    const float* bng  = (const float*)d_in[9];
    const float* bnb  = (const float*)d_in[10];
    const float* fcW  = (const float*)d_in[11];
    const float* fcb  = (const float*)d_in[12];
    float* out = (float*)d_out;
    const int* srcp = edges;
    const int* dstp = edges + N_EDGES;

    char* p = (char*)d_ws;
    auto alloc = [&](size_t bytes) -> char* {
        char* r = p;
        p += (bytes + 511) & ~(size_t)511;
        return r;
    };
    float* B0      = (float*)alloc((size_t)N_NODES * D * 4);  // agg, then H (in place)
    float* B1      = (float*)alloc((size_t)N_NODES * D * 4);  // x buffer
    int*   csr     = (int*)alloc((size_t)N_EDGES * 4);
    int*   deg     = (int*)alloc((size_t)N_NODES * 4);
    int*   offsets = (int*)alloc((size_t)(N_NODES + 1) * 4);
    int*   cursor  = (int*)alloc((size_t)N_NODES * 4);
    int*   bsum    = (int*)alloc((size_t)NB * 4);
    int*   boff    = (int*)alloc((size_t)NB * 4);
    float* colsum  = (float*)alloc(D * 4);
    float* colsq   = (float*)alloc(D * 4);
    float* scalev  = (float*)alloc(D * 4);
    float* shiftv  = (float*)alloc(D * 4);
    int*   gs      = (int*)alloc(N_GRAPHS * 4);
    int*   ge      = (int*)alloc(N_GRAPHS * 4);
    float* pooled  = (float*)alloc((size_t)N_GRAPHS * D * 4);
    float* pscale  = (float*)alloc(D * 4);
    float* pshift  = (float*)alloc(D * 4);

    hipMemsetAsync(deg, 0, (size_t)N_NODES * 4, stream);
    hist_kernel<<<2048, 256, 0, stream>>>(dstp, deg);
    scan_block_sum<<<NB, 256, 0, stream>>>(deg, bsum);
    scan_top<<<1, 512, 0, stream>>>(bsum, boff);
    scan_apply<<<NB, 256, 0, stream>>>(deg, boff, offsets, cursor);
    csr_fill<<<2048, 256, 0, stream>>>(srcp, dstp, cursor, csr);

    const int GEMM_GRID = (N_NODES + BM - 1) / BM;  // 782
    const float* xcur = x_in;
    for (int l = 0; l < 3; ++l) {
        agg_kernel<<<2048, 256, 0, stream>>>(xcur, csr, offsets, B0);
        hipMemsetAsync(colsum, 0, D * 4, stream);
        hipMemsetAsync(colsq, 0, D * 4, stream);
        gemm1_kernel<<<GEMM_GRID, 512, 0, stream>>>(B0, W1 + (size_t)l * D * D, b1 + l * D,
                                                    colsum, colsq);
        bn_fin<<<1, D, 0, stream>>>(colsum, colsq, g1 + l * D, bt1 + l * D, scalev, shiftv,
                                    1.0f / N_NODES);
        gemm2_kernel<<<GEMM_GRID, 512, 0, stream>>>(B0, W2 + (size_t)l * D * D, b2 + l * D,
                                                    scalev, shiftv, xcur, B1);
        xcur = B1;
    }

    hipMemsetAsync(gs, 0x7f, N_GRAPHS * 4, stream);
    hipMemsetAsync(ge, 0, N_GRAPHS * 4, stream);
    bounds_kernel<<<256, 256, 0, stream>>>(batch, gs, ge);
    pool_kernel<<<N_GRAPHS, D, 0, stream>>>(xcur, gs, ge, pooled);
    pooled_bn<<<1, D, 0, stream>>>(pooled, bng, bnb, pscale, pshift);
    out_kernel<<<(N_GRAPHS * LATENT + 255) / 256, 256, 0, stream>>>(pooled, pscale, pshift,
                                                                    fcW, fcb, out);
}

// Round 2
// 1205.290 us; speedup vs baseline: 1.3746x; 1.3746x over previous
//
#include <hip/hip_runtime.h>

#define N_NODES 100000
#define N_EDGES 1600000
#define N_GRAPHS 1000
#define D 128
#define LATENT 64
#define EPS 1e-5f
#define NB ((N_NODES + 255) / 256)   // 391
#define BM 128
#define LDP 132                       // padded LDS row (floats), 16B-aligned rows

// ---------------- CSR build ----------------

__global__ void hist_kernel(const int* __restrict__ dst, int* __restrict__ deg) {
    for (int e = blockIdx.x * blockDim.x + threadIdx.x; e < N_EDGES; e += gridDim.x * blockDim.x)
        atomicAdd(&deg[dst[e]], 1);
}

__global__ void scan_block_sum(const int* __restrict__ deg, int* __restrict__ bsum) {
    __shared__ int s[256];
    int t = threadIdx.x;
    int i = blockIdx.x * 256 + t;
    s[t] = (i < N_NODES) ? deg[i] : 0;
    __syncthreads();
    for (int off = 128; off > 0; off >>= 1) {
        if (t < off) s[t] += s[t + off];
        __syncthreads();
    }
    if (t == 0) bsum[blockIdx.x] = s[0];
}

__global__ void scan_top(const int* __restrict__ bsum, int* __restrict__ boff) {
    __shared__ int s[512];
    int t = threadIdx.x;
    int v = (t < NB) ? bsum[t] : 0;
    s[t] = v;
    __syncthreads();
    for (int off = 1; off < 512; off <<= 1) {
        int add = (t >= off) ? s[t - off] : 0;
        __syncthreads();
        s[t] += add;
        __syncthreads();
    }
    if (t < NB) boff[t] = s[t] - v;
}

__global__ void scan_apply(const int* __restrict__ deg, const int* __restrict__ boff,
                           int* __restrict__ offsets, int* __restrict__ cursor) {
    __shared__ int s[256];
    int t = threadIdx.x;
    int i = blockIdx.x * 256 + t;
    int v = (i < N_NODES) ? deg[i] : 0;
    s[t] = v;
    __syncthreads();
    for (int off = 1; off < 256; off <<= 1) {
        int add = (t >= off) ? s[t - off] : 0;
        __syncthreads();
        s[t] += add;
        __syncthreads();
    }
    int base = boff[blockIdx.x];
    if (i < N_NODES) {
        int ex = base + s[t] - v;
        offsets[i] = ex;
        cursor[i] = ex;
    }
    if (i == N_NODES - 1) offsets[N_NODES] = base + s[t];
}

__global__ void csr_fill(const int* __restrict__ src, const int* __restrict__ dst,
                         int* __restrict__ cursor, int* __restrict__ csr) {
    for (int e = blockIdx.x * blockDim.x + threadIdx.x; e < N_EDGES; e += gridDim.x * blockDim.x) {
        int d = dst[e];
        int p = atomicAdd(&cursor[d], 1);
        csr[p] = src[e];
    }
}

// ---------------- aggregation: agg = x + sum_{j->i} x_j ----------------
// 32 lanes per node, float4 per lane; edge loop unrolled x4 -> 4 independent
// 16B loads in flight per thread (64B MLP) to hide L2-miss latency.

__global__ void agg_kernel(const float* __restrict__ x, const int* __restrict__ csr,
                           const int* __restrict__ offsets, float* __restrict__ agg) {
    int node = (blockIdx.x * blockDim.x + threadIdx.x) >> 5;
    if (node >= N_NODES) return;
    int f4 = (threadIdx.x & 31) << 2;
    int s = offsets[node], e = offsets[node + 1];
    const float* xp = x + f4;
    float4 acc = *(const float4*)&xp[(size_t)node * D];
    int p = s;
    for (; p + 4 <= e; p += 4) {
        int j0 = csr[p], j1 = csr[p + 1], j2 = csr[p + 2], j3 = csr[p + 3];
        float4 a0 = *(const float4*)&xp[(size_t)j0 * D];
        float4 a1 = *(const float4*)&xp[(size_t)j1 * D];
        float4 a2 = *(const float4*)&xp[(size_t)j2 * D];
        float4 a3 = *(const float4*)&xp[(size_t)j3 * D];
        acc.x += (a0.x + a1.x) + (a2.x + a3.x);
        acc.y += (a0.y + a1.y) + (a2.y + a3.y);
        acc.z += (a0.z + a1.z) + (a2.z + a3.z);
        acc.w += (a0.w + a1.w) + (a2.w + a3.w);
    }
    for (; p < e; ++p) {
        int j = csr[p];
        float4 a = *(const float4*)&xp[(size_t)j * D];
        acc.x += a.x; acc.y += a.y; acc.z += a.z; acc.w += a.w;
    }
    *(float4*)&agg[(size_t)node * D + f4] = acc;
}

// ---------------- GEMM1: H = leaky(A @ W + b), in-place over A; fused BN col stats ----------------
// 512 threads, 128-row tile, full K=128. Thread micro-tile: 4 rows x 8 cols
// (cols c0..c0+3 and c0+64..c0+67, c0 = (tid&15)*4 -> conflict-free LDS W reads).

__global__ __launch_bounds__(512, 1)
void gemm1_kernel(float* AH, const float* __restrict__ W, const float* __restrict__ bias,
                  float* __restrict__ colsum, float* __restrict__ colsq) {
    __shared__ float As[BM][LDP];
    __shared__ float Ws[D][LDP];
    __shared__ float csum[D], csq[D];
    int tid = threadIdx.x;
    int row0 = blockIdx.x * BM;
#pragma unroll
    for (int j = 0; j < 8; ++j) {
        int o = (j * 512 + tid) * 4;
        int k = o >> 7, c = o & 127;
        *(float4*)&Ws[k][c] = *(const float4*)&W[o];
        float4 a = make_float4(0.f, 0.f, 0.f, 0.f);
        if (row0 + k < N_NODES) a = *(const float4*)&AH[(size_t)(row0 + k) * D + c];
        *(float4*)&As[k][c] = a;
    }
    if (tid < D) { csum[tid] = 0.f; csq[tid] = 0.f; }
    __syncthreads();

    int c0 = (tid & 15) * 4;
    int r0 = (tid >> 4) * 4;
    float acc[4][8];
#pragma unroll
    for (int i = 0; i < 4; ++i)
#pragma unroll
        for (int j = 0; j < 8; ++j) acc[i][j] = 0.f;

    for (int k = 0; k < D; k += 4) {
        float a[4][4];
#pragma unroll
        for (int i = 0; i < 4; ++i) {
            float4 t = *(float4*)&As[r0 + i][k];
            a[i][0] = t.x; a[i][1] = t.y; a[i][2] = t.z; a[i][3] = t.w;
        }
#pragma unroll
        for (int kk = 0; kk < 4; ++kk) {
            float4 w0 = *(float4*)&Ws[k + kk][c0];
            float4 w1 = *(float4*)&Ws[k + kk][c0 + 64];
#pragma unroll
            for (int i = 0; i < 4; ++i) {
                float av = a[i][kk];
                acc[i][0] += av * w0.x; acc[i][1] += av * w0.y;
                acc[i][2] += av * w0.z; acc[i][3] += av * w0.w;
                acc[i][4] += av * w1.x; acc[i][5] += av * w1.y;
                acc[i][6] += av * w1.z; acc[i][7] += av * w1.w;
            }
        }
    }

    int cols[8];
#pragma unroll
    for (int j = 0; j < 8; ++j) cols[j] = c0 + (j >> 2) * 64 + (j & 3);
    float bs[8], ls[8], lq[8];
#pragma unroll
    for (int j = 0; j < 8; ++j) { bs[j] = bias[cols[j]]; ls[j] = 0.f; lq[j] = 0.f; }

#pragma unroll
    for (int i = 0; i < 4; ++i) {
        int gr = row0 + r0 + i;
        if (gr < N_NODES) {
            float v[8];
#pragma unroll
            for (int j = 0; j < 8; ++j) {
                float z = acc[i][j] + bs[j];
                z = (z >= 0.f) ? z : 0.2f * z;
                v[j] = z;
                ls[j] += z; lq[j] += z * z;
            }
            *(float4*)&AH[(size_t)gr * D + c0]      = make_float4(v[0], v[1], v[2], v[3]);
            *(float4*)&AH[(size_t)gr * D + c0 + 64] = make_float4(v[4], v[5], v[6], v[7]);
        }
    }
    // reduce lanes sharing same c0 within wave (lanes l, l+16, l+32, l+48)
#pragma unroll
    for (int j = 0; j < 8; ++j) {
        ls[j] += __shfl_down(ls[j], 32);
        ls[j] += __shfl_down(ls[j], 16);
        lq[j] += __shfl_down(lq[j], 32);
        lq[j] += __shfl_down(lq[j], 16);
    }
    if ((tid & 63) < 16) {
#pragma unroll
        for (int j = 0; j < 8; ++j) {
            atomicAdd(&csum[cols[j]], ls[j]);
            atomicAdd(&csq[cols[j]], lq[j]);
        }
    }
    __syncthreads();
    if (tid < D) {
        atomicAdd(&colsum[tid], csum[tid]);
        atomicAdd(&colsq[tid], csq[tid]);
    }
}

// ---------------- BN finalize ----------------

__global__ void bn_fin(const float* __restrict__ colsum, const float* __restrict__ colsq,
                       const float* __restrict__ g, const float* __restrict__ bt,
                       float* __restrict__ scale, float* __restrict__ shift, float inv_n) {
    int c = threadIdx.x;
    float m = colsum[c] * inv_n;
    float var = colsq[c] * inv_n - m * m;
    var = fmaxf(var, 0.f);
    float sc = g[c] * rsqrtf(var + EPS);
    scale[c] = sc;
    shift[c] = bt[c] - m * sc;
}

// ---------------- GEMM2: X = leaky(BN(H) @ W + b) + x_res ----------------

__global__ __launch_bounds__(512, 1)
void gemm2_kernel(const float* __restrict__ H, const float* __restrict__ W,
                  const float* __restrict__ bias, const float* __restrict__ scale,
                  const float* __restrict__ shift, const float* xres, float* xout) {
    __shared__ float As[BM][LDP];
    __shared__ float Ws[D][LDP];
    int tid = threadIdx.x;
    int row0 = blockIdx.x * BM;
#pragma unroll
    for (int j = 0; j < 8; ++j) {
        int o = (j * 512 + tid) * 4;
        int k = o >> 7, c = o & 127;
        *(float4*)&Ws[k][c] = *(const float4*)&W[o];
        float4 a = make_float4(0.f, 0.f, 0.f, 0.f);
        if (row0 + k < N_NODES) {
            a = *(const float4*)&H[(size_t)(row0 + k) * D + c];
            a.x = a.x * scale[c] + shift[c];
            a.y = a.y * scale[c + 1] + shift[c + 1];
            a.z = a.z * scale[c + 2] + shift[c + 2];
            a.w = a.w * scale[c + 3] + shift[c + 3];
        }
        *(float4*)&As[k][c] = a;
    }
    __syncthreads();

    int c0 = (tid & 15) * 4;
    int r0 = (tid >> 4) * 4;
    float acc[4][8];
#pragma unroll
    for (int i = 0; i < 4; ++i)
#pragma unroll
        for (int j = 0; j < 8; ++j) acc[i][j] = 0.f;

    for (int k = 0; k < D; k += 4) {
        float a[4][4];
#pragma unroll
        for (int i = 0; i < 4; ++i) {
            float4 t = *(float4*)&As[r0 + i][k];
            a[i][0] = t.x; a[i][1] = t.y; a[i][2] = t.z; a[i][3] = t.w;
        }
#pragma unroll
        for (int kk = 0; kk < 4; ++kk) {
            float4 w0 = *(float4*)&Ws[k + kk][c0];
            float4 w1 = *(float4*)&Ws[k + kk][c0 + 64];
#pragma unroll
            for (int i = 0; i < 4; ++i) {
                float av = a[i][kk];
                acc[i][0] += av * w0.x; acc[i][1] += av * w0.y;
                acc[i][2] += av * w0.z; acc[i][3] += av * w0.w;
                acc[i][4] += av * w1.x; acc[i][5] += av * w1.y;
                acc[i][6] += av * w1.z; acc[i][7] += av * w1.w;
            }
        }
    }

    int cols[8];
#pragma unroll
    for (int j = 0; j < 8; ++j) cols[j] = c0 + (j >> 2) * 64 + (j & 3);
    float bs[8];
#pragma unroll
    for (int j = 0; j < 8; ++j) bs[j] = bias[cols[j]];

#pragma unroll
    for (int i = 0; i < 4; ++i) {
        int gr = row0 + r0 + i;
        if (gr < N_NODES) {
            float4 xr0 = *(const float4*)&xres[(size_t)gr * D + c0];
            float4 xr1 = *(const float4*)&xres[(size_t)gr * D + c0 + 64];
            float v[8];
#pragma unroll
            for (int j = 0; j < 8; ++j) {
                float z = acc[i][j] + bs[j];
                v[j] = (z >= 0.f) ? z : 0.2f * z;
            }
            v[0] += xr0.x; v[1] += xr0.y; v[2] += xr0.z; v[3] += xr0.w;
            v[4] += xr1.x; v[5] += xr1.y; v[6] += xr1.z; v[7] += xr1.w;
            *(float4*)&xout[(size_t)gr * D + c0]      = make_float4(v[0], v[1], v[2], v[3]);
            *(float4*)&xout[(size_t)gr * D + c0 + 64] = make_float4(v[4], v[5], v[6], v[7]);
        }
    }
}

// ---------------- pooling + final BN + fc ----------------

__global__ void bounds_kernel(const int* __restrict__ batch, int* __restrict__ gs, int* __restrict__ ge) {
    for (int i = blockIdx.x * blockDim.x + threadIdx.x; i < N_NODES; i += gridDim.x * blockDim.x) {
        int b = batch[i];
        atomicMin(&gs[b], i);
        atomicMax(&ge[b], i + 1);
    }
}

__global__ void pool_kernel(const float* __restrict__ x, const int* __restrict__ gs,
                            const int* __restrict__ ge, float* __restrict__ pooled) {
    int g = blockIdx.x, f = threadIdx.x;
    int s = gs[g], e = ge[g];
    float acc = 0.f;
    for (int i = s; i < e; ++i) acc += x[(size_t)i * D + f];
    pooled[g * D + f] = acc;
}

__global__ void pooled_bn(const float* __restrict__ pooled, const float* __restrict__ g,
                          const float* __restrict__ b, float* __restrict__ pscale,
                          float* __restrict__ pshift) {
    int c = threadIdx.x;
    float s = 0.f, q = 0.f;
    for (int gi = 0; gi < N_GRAPHS; ++gi) {
        float v = pooled[gi * D + c];
        s += v; q += v * v;
    }
    float m = s / N_GRAPHS;
    float var = q / N_GRAPHS - m * m;
    var = fmaxf(var, 0.f);
    float sc = g[c] * rsqrtf(var + EPS);
    pscale[c] = sc;
    pshift[c] = b[c] - m * sc;
}

__global__ void out_kernel(const float* __restrict__ pooled, const float* __restrict__ pscale,
                           const float* __restrict__ pshift, const float* __restrict__ fcW,
                           const float* __restrict__ fcb, float* __restrict__ out) {
    int idx = blockIdx.x * blockDim.x + threadIdx.x;
    if (idx >= N_GRAPHS * LATENT) return;
    int g = idx >> 6, j = idx & 63;
    float acc = fcb[j];
    for (int c = 0; c < D; ++c) {
        float pv = pooled[g * D + c] * pscale[c] + pshift[c];
        acc += pv * fcW[c * LATENT + j];
    }
    out[idx] = acc;
}

// ---------------- launch ----------------

extern "C" void kernel_launch(void* const* d_in, const int* in_sizes, int n_in,
                              void* d_out, int out_size, void* d_ws, size_t ws_size,
                              hipStream_t stream) {
    const float* x_in = (const float*)d_in[0];
    const int* edges  = (const int*)d_in[1];
    const int* batch  = (const int*)d_in[2];
    const float* W1   = (const float*)d_in[3];
    const float* b1   = (const float*)d_in[4];
    const float* g1   = (const float*)d_in[5];
    const float* bt1  = (const float*)d_in[6];
    const float* W2   = (const float*)d_in[7];
    const float* b2   = (const float*)d_in[8];
    const float* bng  = (const float*)d_in[9];
    const float* bnb  = (const float*)d_in[10];
    const float* fcW  = (const float*)d_in[11];
    const float* fcb  = (const float*)d_in[12];
    float* out = (float*)d_out;
    const int* srcp = edges;
    const int* dstp = edges + N_EDGES;

    char* p = (char*)d_ws;
    auto alloc = [&](size_t bytes) -> char* {
        char* r = p;
        p += (bytes + 511) & ~(size_t)511;
        return r;
    };
    float* B0      = (float*)alloc((size_t)N_NODES * D * 4);  // agg, then H (in place)
    float* B1      = (float*)alloc((size_t)N_NODES * D * 4);  // x buffer
    int*   csr     = (int*)alloc((size_t)N_EDGES * 4);
    int*   deg     = (int*)alloc((size_t)N_NODES * 4);
    int*   offsets = (int*)alloc((size_t)(N_NODES + 1) * 4);
    int*   cursor  = (int*)alloc((size_t)N_NODES * 4);
    int*   bsum    = (int*)alloc((size_t)NB * 4);
    int*   boff    = (int*)alloc((size_t)NB * 4);
    float* colsum  = (float*)alloc(D * 4);
    float* colsq   = (float*)alloc(D * 4);
    float* scalev  = (float*)alloc(D * 4);
    float* shiftv  = (float*)alloc(D * 4);
    int*   gs      = (int*)alloc(N_GRAPHS * 4);
    int*   ge      = (int*)alloc(N_GRAPHS * 4);
    float* pooled  = (float*)alloc((size_t)N_GRAPHS * D * 4);
    float* pscale  = (float*)alloc(D * 4);
    float* pshift  = (float*)alloc(D * 4);

    hipMemsetAsync(deg, 0, (size_t)N_NODES * 4, stream);
    hist_kernel<<<2048, 256, 0, stream>>>(dstp, deg);
    scan_block_sum<<<NB, 256, 0, stream>>>(deg, bsum);
    scan_top<<<1, 512, 0, stream>>>(bsum, boff);
    scan_apply<<<NB, 256, 0, stream>>>(deg, boff, offsets, cursor);
    csr_fill<<<2048, 256, 0, stream>>>(srcp, dstp, cursor, csr);

    const int GEMM_GRID = (N_NODES + BM - 1) / BM;  // 782
    const int AGG_GRID = (N_NODES * 32 + 255) / 256;  // 12500
    const float* xcur = x_in;
    for (int l = 0; l < 3; ++l) {
        agg_kernel<<<AGG_GRID, 256, 0, stream>>>(xcur, csr, offsets, B0);
        hipMemsetAsync(colsum, 0, D * 4, stream);
        hipMemsetAsync(colsq, 0, D * 4, stream);
        gemm1_kernel<<<GEMM_GRID, 512, 0, stream>>>(B0, W1 + (size_t)l * D * D, b1 + l * D,
                                                    colsum, colsq);
        bn_fin<<<1, D, 0, stream>>>(colsum, colsq, g1 + l * D, bt1 + l * D, scalev, shiftv,
                                    1.0f / N_NODES);
        gemm2_kernel<<<GEMM_GRID, 512, 0, stream>>>(B0, W2 + (size_t)l * D * D, b2 + l * D,
                                                    scalev, shiftv, xcur, B1);
        xcur = B1;
    }

    hipMemsetAsync(gs, 0x7f, N_GRAPHS * 4, stream);
    hipMemsetAsync(ge, 0, N_GRAPHS * 4, stream);
    bounds_kernel<<<256, 256, 0, stream>>>(batch, gs, ge);
    pool_kernel<<<N_GRAPHS, D, 0, stream>>>(xcur, gs, ge, pooled);
    pooled_bn<<<1, D, 0, stream>>>(pooled, bng, bnb, pscale, pshift);
    out_kernel<<<(N_GRAPHS * LATENT + 255) / 256, 256, 0, stream>>>(pooled, pscale, pshift,
                                                                    fcW, fcb, out);
}

// Round 3
// 701.217 us; speedup vs baseline: 2.3627x; 1.7189x over previous
//
#include <hip/hip_runtime.h>

#define N_NODES 100000
#define N_EDGES 1600000
#define N_GRAPHS 1000
#define D 128
#define LATENT 64
#define EPS 1e-5f
#define NB ((N_NODES + 255) / 256)   // 391

typedef unsigned short u16;
typedef unsigned int u32;
typedef __attribute__((ext_vector_type(8))) short short8;   // 8 bf16 = 4 VGPR (MFMA A/B frag)
typedef __attribute__((ext_vector_type(4))) float f32x4;    // MFMA C/D frag

__device__ __forceinline__ float bf2f(u32 u) {
    union { u32 i; float f; } c; c.i = u << 16; return c.f;
}
__device__ __forceinline__ u16 f2bf(float f) {
    union { float f; u32 u; } c; c.f = f;
    u32 u = c.u;
    return (u16)((u + 0x7fffu + ((u >> 16) & 1u)) >> 16);   // RNE
}

// ---------------- weight convert: W[k][n] fp32 -> Wt[n][k] bf16 (6 matrices) ----------------

__global__ void conv_w(const float* __restrict__ W1, const float* __restrict__ W2,
                       u16* __restrict__ Wt) {
    int b = blockIdx.x;
    const float* src = (b < 3) ? (W1 + (size_t)b * D * D) : (W2 + (size_t)(b - 3) * D * D);
    u16* dst = Wt + (size_t)b * D * D;
    for (int i = threadIdx.x; i < D * D; i += blockDim.x) {
        int k = i >> 7, n = i & 127;
        dst[n * D + k] = f2bf(src[i]);
    }
}

// ---------------- x fp32 -> bf16 ----------------

__global__ void conv_x(const float* __restrict__ x, u16* __restrict__ xb) {
    int idx = blockIdx.x * blockDim.x + threadIdx.x;
    if (idx >= N_NODES * D / 4) return;
    float4 v = *(const float4*)&x[(size_t)idx * 4];
    u32 lo = (u32)f2bf(v.x) | ((u32)f2bf(v.y) << 16);
    u32 hi = (u32)f2bf(v.z) | ((u32)f2bf(v.w) << 16);
    *(uint2*)&xb[(size_t)idx * 4] = make_uint2(lo, hi);
}

// ---------------- CSR build ----------------

__global__ void hist_kernel(const int* __restrict__ dst, int* __restrict__ deg) {
    int base = blockIdx.x * 2048 + threadIdx.x;
#pragma unroll
    for (int i = 0; i < 8; ++i) {
        int e = base + i * 256;
        if (e < N_EDGES) atomicAdd(&deg[dst[e]], 1);
    }
}

__global__ void scan_block_sum(const int* __restrict__ deg, int* __restrict__ bsum) {
    __shared__ int s[256];
    int t = threadIdx.x;
    int i = blockIdx.x * 256 + t;
    s[t] = (i < N_NODES) ? deg[i] : 0;
    __syncthreads();
    for (int off = 128; off > 0; off >>= 1) {
        if (t < off) s[t] += s[t + off];
        __syncthreads();
    }
    if (t == 0) bsum[blockIdx.x] = s[0];
}

__global__ void scan_top(const int* __restrict__ bsum, int* __restrict__ boff) {
    __shared__ int s[512];
    int t = threadIdx.x;
    int v = (t < NB) ? bsum[t] : 0;
    s[t] = v;
    __syncthreads();
    for (int off = 1; off < 512; off <<= 1) {
        int add = (t >= off) ? s[t - off] : 0;
        __syncthreads();
        s[t] += add;
        __syncthreads();
    }
    if (t < NB) boff[t] = s[t] - v;
}

__global__ void scan_apply(const int* __restrict__ deg, const int* __restrict__ boff,
                           int* __restrict__ offsets, int* __restrict__ cursor) {
    __shared__ int s[256];
    int t = threadIdx.x;
    int i = blockIdx.x * 256 + t;
    int v = (i < N_NODES) ? deg[i] : 0;
    s[t] = v;
    __syncthreads();
    for (int off = 1; off < 256; off <<= 1) {
        int add = (t >= off) ? s[t - off] : 0;
        __syncthreads();
        s[t] += add;
        __syncthreads();
    }
    int base = boff[blockIdx.x];
    if (i < N_NODES) {
        int ex = base + s[t] - v;
        offsets[i] = ex;
        cursor[i] = ex;
    }
    if (i == N_NODES - 1) offsets[N_NODES] = base + s[t];
}

// 8 edges/thread: load phase -> 8 independent atomics in flight -> store phase.
__global__ void csr_fill(const int* __restrict__ src, const int* __restrict__ dst,
                         int* __restrict__ cursor, int* __restrict__ csr) {
    int base = blockIdx.x * 2048 + threadIdx.x;
    int d[8], s[8], pos[8];
#pragma unroll
    for (int i = 0; i < 8; ++i) {
        int e = base + i * 256;
        d[i] = (e < N_EDGES) ? dst[e] : -1;
        s[i] = (e < N_EDGES) ? src[e] : 0;
    }
#pragma unroll
    for (int i = 0; i < 8; ++i)
        pos[i] = (d[i] >= 0) ? atomicAdd(&cursor[d[i]], 1) : 0;
#pragma unroll
    for (int i = 0; i < 8; ++i)
        if (d[i] >= 0) csr[pos[i]] = s[i];
}

// ---------------- aggregation: ab = bf16( x + sum_{j->i} x_j ), x in bf16 ----------------
// 32 lanes/node, 8B (4 bf16) per lane, fp32 accumulate, 4-deep unroll for MLP.

__global__ void agg_kernel(const u16* __restrict__ xb, const int* __restrict__ csr,
                           const int* __restrict__ offsets, u16* __restrict__ ab) {
    int node = (blockIdx.x * blockDim.x + threadIdx.x) >> 5;
    if (node >= N_NODES) return;
    int lane = threadIdx.x & 31;
    const u16* xp = xb + lane * 4;
    uint2 sv = *(const uint2*)&xp[(size_t)node * D];
    float a0 = bf2f(sv.x & 0xffff), a1 = bf2f(sv.x >> 16);
    float a2 = bf2f(sv.y & 0xffff), a3 = bf2f(sv.y >> 16);
    int s = offsets[node], e = offsets[node + 1];
    int p = s;
    for (; p + 4 <= e; p += 4) {
        int j0 = csr[p], j1 = csr[p + 1], j2 = csr[p + 2], j3 = csr[p + 3];
        uint2 v0 = *(const uint2*)&xp[(size_t)j0 * D];
        uint2 v1 = *(const uint2*)&xp[(size_t)j1 * D];
        uint2 v2 = *(const uint2*)&xp[(size_t)j2 * D];
        uint2 v3 = *(const uint2*)&xp[(size_t)j3 * D];
        a0 += (bf2f(v0.x & 0xffff) + bf2f(v1.x & 0xffff)) + (bf2f(v2.x & 0xffff) + bf2f(v3.x & 0xffff));
        a1 += (bf2f(v0.x >> 16) + bf2f(v1.x >> 16)) + (bf2f(v2.x >> 16) + bf2f(v3.x >> 16));
        a2 += (bf2f(v0.y & 0xffff) + bf2f(v1.y & 0xffff)) + (bf2f(v2.y & 0xffff) + bf2f(v3.y & 0xffff));
        a3 += (bf2f(v0.y >> 16) + bf2f(v1.y >> 16)) + (bf2f(v2.y >> 16) + bf2f(v3.y >> 16));
    }
    for (; p < e; ++p) {
        uint2 v = *(const uint2*)&xp[(size_t)csr[p] * D];
        a0 += bf2f(v.x & 0xffff); a1 += bf2f(v.x >> 16);
        a2 += bf2f(v.y & 0xffff); a3 += bf2f(v.y >> 16);
    }
    u32 lo = (u32)f2bf(a0) | ((u32)f2bf(a1) << 16);
    u32 hi = (u32)f2bf(a2) | ((u32)f2bf(a3) << 16);
    *(uint2*)&ab[(size_t)node * D + lane * 4] = make_uint2(lo, hi);
}

// ---------------- MFMA GEMM common geometry ----------------
// 256 thr = 4 waves, BM=128, N=128, K=128. Wave (wid): rows (wid>>1)*64, cols (wid&1)*64.
// Per wave: 4x4 tiles of 16x16, K in 4 steps of 32. LDS [row][k] bf16, 256B rows,
// XOR-swizzle byte ^= ((row&15)<<4) -> conflict-free ds_read_b128 fragments.
// Frag layouts (guide-verified): A row=lane&15, k=(lane>>4)*8+i; B col=lane&15 same k;
// C/D col=lane&15, row=(lane>>4)*4+reg.

// GEMM1: H = leaky(A@W1 + b1) written bf16 IN PLACE over A; fused BN column stats.
__global__ __launch_bounds__(256, 2)
void gemm1_mfma(u16* __restrict__ AB, const u16* __restrict__ Wt,
                const float* __restrict__ bias,
                float* __restrict__ colsum, float* __restrict__ colsq) {
    __shared__ u16 As[128 * 128];
    __shared__ u16 Ws[128 * 128];
    __shared__ float csumL[D], csqL[D];
    int tid = threadIdx.x;
    int row0 = blockIdx.x * 128;

    if (tid < D) { csumL[tid] = 0.f; csqL[tid] = 0.f; }
    const uint4* Wg = (const uint4*)Wt;
#pragma unroll
    for (int i = 0; i < 8; ++i) {
        int q = i * 256 + tid;
        int m = q >> 4, kc = q & 15;
        uint4 wv = Wg[q];
        *(uint4*)((char*)Ws + m * 256 + ((kc * 16) ^ ((m & 15) << 4))) = wv;
        uint4 av = make_uint4(0, 0, 0, 0);
        int gm = row0 + m;
        if (gm < N_NODES) av = *(const uint4*)&AB[(size_t)gm * D + kc * 8];
        *(uint4*)((char*)As + m * 256 + ((kc * 16) ^ ((m & 15) << 4))) = av;
    }
    __syncthreads();

    int lane = tid & 63;
    int wid = tid >> 6;
    int mbase = (wid >> 1) * 64, nbase = (wid & 1) * 64;
    int lr = lane & 15, kg = lane >> 4;
    f32x4 acc[4][4];
#pragma unroll
    for (int mt = 0; mt < 4; ++mt)
#pragma unroll
        for (int nt = 0; nt < 4; ++nt) acc[mt][nt] = (f32x4)0.0f;

    const char* Ap = (const char*)As;
    const char* Wp = (const char*)Ws;
#pragma unroll
    for (int ks = 0; ks < 4; ++ks) {
        int kb2 = ks * 64 + kg * 16;
        short8 af[4], bfr[4];
#pragma unroll
        for (int t = 0; t < 4; ++t) {
            int m = mbase + t * 16 + lr;
            af[t] = *(const short8*)(Ap + m * 256 + (kb2 ^ ((m & 15) << 4)));
            int n = nbase + t * 16 + lr;
            bfr[t] = *(const short8*)(Wp + n * 256 + (kb2 ^ ((n & 15) << 4)));
        }
#pragma unroll
        for (int mt = 0; mt < 4; ++mt)
#pragma unroll
            for (int nt = 0; nt < 4; ++nt)
                acc[mt][nt] = __builtin_amdgcn_mfma_f32_16x16x32_bf16(af[mt], bfr[nt], acc[mt][nt], 0, 0, 0);
    }

    float bv[4], ls[4] = {0, 0, 0, 0}, lq[4] = {0, 0, 0, 0};
#pragma unroll
    for (int nt = 0; nt < 4; ++nt) bv[nt] = bias[nbase + nt * 16 + lr];
#pragma unroll
    for (int mt = 0; mt < 4; ++mt) {
#pragma unroll
        for (int r = 0; r < 4; ++r) {
            int gm = row0 + mbase + mt * 16 + kg * 4 + r;
            if (gm < N_NODES) {
#pragma unroll
                for (int nt = 0; nt < 4; ++nt) {
                    float z = acc[mt][nt][r] + bv[nt];
                    z = (z >= 0.f) ? z : 0.2f * z;
                    AB[(size_t)gm * D + nbase + nt * 16 + lr] = f2bf(z);
                    ls[nt] += z; lq[nt] += z * z;
                }
            }
        }
    }
#pragma unroll
    for (int nt = 0; nt < 4; ++nt) {
        ls[nt] += __shfl_down(ls[nt], 32); ls[nt] += __shfl_down(ls[nt], 16);
        lq[nt] += __shfl_down(lq[nt], 32); lq[nt] += __shfl_down(lq[nt], 16);
    }
    if (lane < 16) {
#pragma unroll
        for (int nt = 0; nt < 4; ++nt) {
            atomicAdd(&csumL[nbase + nt * 16 + lane], ls[nt]);
            atomicAdd(&csqL[nbase + nt * 16 + lane], lq[nt]);
        }
    }
    __syncthreads();
    if (tid < D) {
        atomicAdd(&colsum[tid], csumL[tid]);
        atomicAdd(&colsq[tid], csqL[tid]);
    }
}

// GEMM2: x = leaky(BN(H)@W2 + b2) + xres; writes fp32 x (in-place safe) + bf16 copy.
__global__ __launch_bounds__(256, 2)
void gemm2_mfma(const u16* __restrict__ HB, const u16* __restrict__ Wt,
                const float* __restrict__ bias, const float* __restrict__ scalev,
                const float* __restrict__ shiftv, const float* __restrict__ xres,
                float* __restrict__ xout, u16* __restrict__ xbout) {
    __shared__ u16 As[128 * 128];
    __shared__ u16 Ws[128 * 128];
    int tid = threadIdx.x;
    int row0 = blockIdx.x * 128;

    const uint4* Wg = (const uint4*)Wt;
#pragma unroll
    for (int i = 0; i < 8; ++i) {
        int q = i * 256 + tid;
        int m = q >> 4, kc = q & 15;
        uint4 wv = Wg[q];
        *(uint4*)((char*)Ws + m * 256 + ((kc * 16) ^ ((m & 15) << 4))) = wv;
        uint4 av = make_uint4(0, 0, 0, 0);
        int gm = row0 + m;
        if (gm < N_NODES) {
            uint4 h = *(const uint4*)&HB[(size_t)gm * D + kc * 8];
            float4 s0 = *(const float4*)&scalev[kc * 8];
            float4 s1 = *(const float4*)&scalev[kc * 8 + 4];
            float4 t0 = *(const float4*)&shiftv[kc * 8];
            float4 t1 = *(const float4*)&shiftv[kc * 8 + 4];
            float f0 = bf2f(h.x & 0xffff) * s0.x + t0.x;
            float f1 = bf2f(h.x >> 16)    * s0.y + t0.y;
            float f2 = bf2f(h.y & 0xffff) * s0.z + t0.z;
            float f3 = bf2f(h.y >> 16)    * s0.w + t0.w;
            float f4 = bf2f(h.z & 0xffff) * s1.x + t1.x;
            float f5 = bf2f(h.z >> 16)    * s1.y + t1.y;
            float f6 = bf2f(h.w & 0xffff) * s1.z + t1.z;
            float f7 = bf2f(h.w >> 16)    * s1.w + t1.w;
            av.x = (u32)f2bf(f0) | ((u32)f2bf(f1) << 16);
            av.y = (u32)f2bf(f2) | ((u32)f2bf(f3) << 16);
            av.z = (u32)f2bf(f4) | ((u32)f2bf(f5) << 16);
            av.w = (u32)f2bf(f6) | ((u32)f2bf(f7) << 16);
        }
        *(uint4*)((char*)As + m * 256 + ((kc * 16) ^ ((m & 15) << 4))) = av;
    }
    __syncthreads();

    int lane = tid & 63;
    int wid = tid >> 6;
    int mbase = (wid >> 1) * 64, nbase = (wid & 1) * 64;
    int lr = lane & 15, kg = lane >> 4;
    f32x4 acc[4][4];
#pragma unroll
    for (int mt = 0; mt < 4; ++mt)
#pragma unroll
        for (int nt = 0; nt < 4; ++nt) acc[mt][nt] = (f32x4)0.0f;

    const char* Ap = (const char*)As;
    const char* Wp = (const char*)Ws;
#pragma unroll
    for (int ks = 0; ks < 4; ++ks) {
        int kb2 = ks * 64 + kg * 16;
        short8 af[4], bfr[4];
#pragma unroll
        for (int t = 0; t < 4; ++t) {
            int m = mbase + t * 16 + lr;
            af[t] = *(const short8*)(Ap + m * 256 + (kb2 ^ ((m & 15) << 4)));
            int n = nbase + t * 16 + lr;
            bfr[t] = *(const short8*)(Wp + n * 256 + (kb2 ^ ((n & 15) << 4)));
        }
#pragma unroll
        for (int mt = 0; mt < 4; ++mt)
#pragma unroll
            for (int nt = 0; nt < 4; ++nt)
                acc[mt][nt] = __builtin_amdgcn_mfma_f32_16x16x32_bf16(af[mt], bfr[nt], acc[mt][nt], 0, 0, 0);
    }

    float bv[4];
#pragma unroll
    for (int nt = 0; nt < 4; ++nt) bv[nt] = bias[nbase + nt * 16 + lr];
#pragma unroll
    for (int mt = 0; mt < 4; ++mt) {
#pragma unroll
        for (int r = 0; r < 4; ++r) {
            int gm = row0 + mbase + mt * 16 + kg * 4 + r;
            if (gm < N_NODES) {
#pragma unroll
                for (int nt = 0; nt < 4; ++nt) {
                    int gn = nbase + nt * 16 + lr;
                    float z = acc[mt][nt][r] + bv[nt];
                    z = (z >= 0.f) ? z : 0.2f * z;
                    float o = z + xres[(size_t)gm * D + gn];
                    xout[(size_t)gm * D + gn] = o;
                    xbout[(size_t)gm * D + gn] = f2bf(o);
                }
            }
        }
    }
}

// ---------------- BN finalize ----------------

__global__ void bn_fin(const float* __restrict__ colsum, const float* __restrict__ colsq,
                       const float* __restrict__ g, const float* __restrict__ bt,
                       float* __restrict__ scale, float* __restrict__ shift, float inv_n) {
    int c = threadIdx.x;
    float m = colsum[c] * inv_n;
    float var = colsq[c] * inv_n - m * m;
    var = fmaxf(var, 0.f);
    float sc = g[c] * rsqrtf(var + EPS);
    scale[c] = sc;
    shift[c] = bt[c] - m * sc;
}

// ---------------- pooling + final BN + fc ----------------

__global__ void bounds_kernel(const int* __restrict__ batch, int* __restrict__ gs, int* __restrict__ ge) {
    for (int i = blockIdx.x * blockDim.x + threadIdx.x; i < N_NODES; i += gridDim.x * blockDim.x) {
        int b = batch[i];
        atomicMin(&gs[b], i);
        atomicMax(&ge[b], i + 1);
    }
}

__global__ void pool_kernel(const float* __restrict__ x, const int* __restrict__ gs,
                            const int* __restrict__ ge, float* __restrict__ pooled) {
    int g = blockIdx.x, f = threadIdx.x;
    int s = gs[g], e = ge[g];
    float a0 = 0.f, a1 = 0.f, a2 = 0.f, a3 = 0.f;
    int i = s;
    for (; i + 4 <= e; i += 4) {
        a0 += x[(size_t)i * D + f];
        a1 += x[(size_t)(i + 1) * D + f];
        a2 += x[(size_t)(i + 2) * D + f];
        a3 += x[(size_t)(i + 3) * D + f];
    }
    for (; i < e; ++i) a0 += x[(size_t)i * D + f];
    pooled[g * D + f] = (a0 + a1) + (a2 + a3);
}

__global__ void pooled_bn(const float* __restrict__ pooled, const float* __restrict__ g,
                          const float* __restrict__ b, float* __restrict__ pscale,
                          float* __restrict__ pshift) {
    int c = threadIdx.x;
    float s = 0.f, q = 0.f;
    for (int gi = 0; gi < N_GRAPHS; ++gi) {
        float v = pooled[gi * D + c];
        s += v; q += v * v;
    }
    float m = s / N_GRAPHS;
    float var = q / N_GRAPHS - m * m;
    var = fmaxf(var, 0.f);
    float sc = g[c] * rsqrtf(var + EPS);
    pscale[c] = sc;
    pshift[c] = b[c] - m * sc;
}

__global__ void out_kernel(const float* __restrict__ pooled, const float* __restrict__ pscale,
                           const float* __restrict__ pshift, const float* __restrict__ fcW,
                           const float* __restrict__ fcb, float* __restrict__ out) {
    int idx = blockIdx.x * blockDim.x + threadIdx.x;
    if (idx >= N_GRAPHS * LATENT) return;
    int g = idx >> 6, j = idx & 63;
    float acc = fcb[j];
    for (int c = 0; c < D; ++c) {
        float pv = pooled[g * D + c] * pscale[c] + pshift[c];
        acc += pv * fcW[c * LATENT + j];
    }
    out[idx] = acc;
}

// ---------------- launch ----------------

extern "C" void kernel_launch(void* const* d_in, const int* in_sizes, int n_in,
                              void* d_out, int out_size, void* d_ws, size_t ws_size,
                              hipStream_t stream) {
    const float* x_in = (const float*)d_in[0];
    const int* edges  = (const int*)d_in[1];
    const int* batch  = (const int*)d_in[2];
    const float* W1   = (const float*)d_in[3];
    const float* b1   = (const float*)d_in[4];
    const float* g1   = (const float*)d_in[5];
    const float* bt1  = (const float*)d_in[6];
    const float* W2   = (const float*)d_in[7];
    const float* b2   = (const float*)d_in[8];
    const float* bng  = (const float*)d_in[9];
    const float* bnb  = (const float*)d_in[10];
    const float* fcW  = (const float*)d_in[11];
    const float* fcb  = (const float*)d_in[12];
    float* out = (float*)d_out;
    const int* srcp = edges;
    const int* dstp = edges + N_EDGES;

    char* p = (char*)d_ws;
    auto alloc = [&](size_t bytes) -> char* {
        char* r = p;
        p += (bytes + 511) & ~(size_t)511;
        return r;
    };
    float* XF      = (float*)alloc((size_t)N_NODES * D * 4);   // fp32 residual stream x
    u16*   XB      = (u16*)alloc((size_t)N_NODES * D * 2);     // bf16 copy of x (gather input)
    u16*   AB      = (u16*)alloc((size_t)N_NODES * D * 2);     // agg out -> H (in place)
    int*   csr     = (int*)alloc((size_t)N_EDGES * 4);
    int*   deg     = (int*)alloc((size_t)N_NODES * 4);
    int*   offsets = (int*)alloc((size_t)(N_NODES + 1) * 4);
    int*   cursor  = (int*)alloc((size_t)N_NODES * 4);
    int*   bsum    = (int*)alloc((size_t)NB * 4);
    int*   boff    = (int*)alloc((size_t)NB * 4);
    u16*   Wtb     = (u16*)alloc((size_t)6 * D * D * 2);       // bf16 transposed weights
    float* colsum  = (float*)alloc(D * 4);
    float* colsq   = (float*)alloc(D * 4);
    float* scalev  = (float*)alloc(D * 4);
    float* shiftv  = (float*)alloc(D * 4);
    int*   gs      = (int*)alloc(N_GRAPHS * 4);
    int*   ge      = (int*)alloc(N_GRAPHS * 4);
    float* pooled  = (float*)alloc((size_t)N_GRAPHS * D * 4);
    float* pscale  = (float*)alloc(D * 4);
    float* pshift  = (float*)alloc(D * 4);

    conv_w<<<6, 256, 0, stream>>>(W1, W2, Wtb);
    conv_x<<<(N_NODES * D / 4 + 255) / 256, 256, 0, stream>>>(x_in, XB);

    hipMemsetAsync(deg, 0, (size_t)N_NODES * 4, stream);
    const int EDGE_GRID = (N_EDGES + 2047) / 2048;  // 782
    hist_kernel<<<EDGE_GRID, 256, 0, stream>>>(dstp, deg);
    scan_block_sum<<<NB, 256, 0, stream>>>(deg, bsum);
    scan_top<<<1, 512, 0, stream>>>(bsum, boff);
    scan_apply<<<NB, 256, 0, stream>>>(deg, boff, offsets, cursor);
    csr_fill<<<EDGE_GRID, 256, 0, stream>>>(srcp, dstp, cursor, csr);

    const int GEMM_GRID = (N_NODES + 127) / 128;    // 782
    const int AGG_GRID = (N_NODES * 32 + 255) / 256; // 12500
    for (int l = 0; l < 3; ++l) {
        agg_kernel<<<AGG_GRID, 256, 0, stream>>>(XB, csr, offsets, AB);
        hipMemsetAsync(colsum, 0, D * 4, stream);
        hipMemsetAsync(colsq, 0, D * 4, stream);
        gemm1_mfma<<<GEMM_GRID, 256, 0, stream>>>(AB, Wtb + (size_t)l * D * D, b1 + l * D,
                                                  colsum, colsq);
        bn_fin<<<1, D, 0, stream>>>(colsum, colsq, g1 + l * D, bt1 + l * D, scalev, shiftv,
                                    1.0f / N_NODES);
        const float* xr = (l == 0) ? x_in : XF;
        gemm2_mfma<<<GEMM_GRID, 256, 0, stream>>>(AB, Wtb + (size_t)(3 + l) * D * D, b2 + l * D,
                                                  scalev, shiftv, xr, XF, XB);
    }

    hipMemsetAsync(gs, 0x7f, N_GRAPHS * 4, stream);
    hipMemsetAsync(ge, 0, N_GRAPHS * 4, stream);
    bounds_kernel<<<256, 256, 0, stream>>>(batch, gs, ge);
    pool_kernel<<<N_GRAPHS, D, 0, stream>>>(XF, gs, ge, pooled);
    pooled_bn<<<1, D, 0, stream>>>(pooled, bng, bnb, pscale, pshift);
    out_kernel<<<(N_GRAPHS * LATENT + 255) / 256, 256, 0, stream>>>(pooled, pscale, pshift,
                                                                    fcW, fcb, out);
}

// Round 4
// 689.997 us; speedup vs baseline: 2.4011x; 1.0163x over previous
//
#include <hip/hip_runtime.h>

#define N_NODES 100000
#define N_EDGES 1600000
#define N_GRAPHS 1000
#define D 128
#define LATENT 64
#define EPS 1e-5f
#define NB ((N_NODES + 255) / 256)   // 391

typedef unsigned short u16;
typedef unsigned int u32;
typedef __attribute__((ext_vector_type(8))) short short8;   // 8 bf16 = 4 VGPR (MFMA A/B frag)
typedef __attribute__((ext_vector_type(4))) float f32x4;    // MFMA C/D frag

__device__ __forceinline__ float bf2f(u32 u) {
    union { u32 i; float f; } c; c.i = u << 16; return c.f;
}
__device__ __forceinline__ u16 f2bf(float f) {
    union { float f; u32 u; } c; c.f = f;
    u32 u = c.u;
    return (u16)((u + 0x7fffu + ((u >> 16) & 1u)) >> 16);   // RNE
}

// ---------------- weight convert: W[k][n] fp32 -> Wt[n][k] bf16 (6 matrices) ----------------

__global__ void conv_w(const float* __restrict__ W1, const float* __restrict__ W2,
                       u16* __restrict__ Wt) {
    int b = blockIdx.x;
    const float* src = (b < 3) ? (W1 + (size_t)b * D * D) : (W2 + (size_t)(b - 3) * D * D);
    u16* dst = Wt + (size_t)b * D * D;
    for (int i = threadIdx.x; i < D * D; i += blockDim.x) {
        int k = i >> 7, n = i & 127;
        dst[n * D + k] = f2bf(src[i]);
    }
}

// ---------------- x fp32 -> bf16 ----------------

__global__ void conv_x(const float* __restrict__ x, u16* __restrict__ xb) {
    int idx = blockIdx.x * blockDim.x + threadIdx.x;
    if (idx >= N_NODES * D / 4) return;
    float4 v = *(const float4*)&x[(size_t)idx * 4];
    u32 lo = (u32)f2bf(v.x) | ((u32)f2bf(v.y) << 16);
    u32 hi = (u32)f2bf(v.z) | ((u32)f2bf(v.w) << 16);
    *(uint2*)&xb[(size_t)idx * 4] = make_uint2(lo, hi);
}

// ---------------- CSR build ----------------
// batch=4/thread (fits registers -> real MLP), grid 1563 -> ~24 waves/CU.

__global__ void hist_kernel(const int* __restrict__ dst, int* __restrict__ deg) {
    int base = blockIdx.x * 1024 + threadIdx.x;
    int d[4];
#pragma unroll
    for (int i = 0; i < 4; ++i) {
        int e = base + i * 256;
        d[i] = (e < N_EDGES) ? dst[e] : -1;
    }
#pragma unroll
    for (int i = 0; i < 4; ++i)
        if (d[i] >= 0) atomicAdd(&deg[d[i]], 1);
}

__global__ void scan_block_sum(const int* __restrict__ deg, int* __restrict__ bsum) {
    __shared__ int s[256];
    int t = threadIdx.x;
    int i = blockIdx.x * 256 + t;
    s[t] = (i < N_NODES) ? deg[i] : 0;
    __syncthreads();
    for (int off = 128; off > 0; off >>= 1) {
        if (t < off) s[t] += s[t + off];
        __syncthreads();
    }
    if (t == 0) bsum[blockIdx.x] = s[0];
}

__global__ void scan_top(const int* __restrict__ bsum, int* __restrict__ boff) {
    __shared__ int s[512];
    int t = threadIdx.x;
    int v = (t < NB) ? bsum[t] : 0;
    s[t] = v;
    __syncthreads();
    for (int off = 1; off < 512; off <<= 1) {
        int add = (t >= off) ? s[t - off] : 0;
        __syncthreads();
        s[t] += add;
        __syncthreads();
    }
    if (t < NB) boff[t] = s[t] - v;
}

__global__ void scan_apply(const int* __restrict__ deg, const int* __restrict__ boff,
                           int* __restrict__ offsets, int* __restrict__ cursor) {
    __shared__ int s[256];
    int t = threadIdx.x;
    int i = blockIdx.x * 256 + t;
    int v = (i < N_NODES) ? deg[i] : 0;
    s[t] = v;
    __syncthreads();
    for (int off = 1; off < 256; off <<= 1) {
        int add = (t >= off) ? s[t - off] : 0;
        __syncthreads();
        s[t] += add;
        __syncthreads();
    }
    int base = boff[blockIdx.x];
    if (i < N_NODES) {
        int ex = base + s[t] - v;
        offsets[i] = ex;
        cursor[i] = ex;
    }
    if (i == N_NODES - 1) offsets[N_NODES] = base + s[t];
}

__global__ void csr_fill(const int* __restrict__ src, const int* __restrict__ dst,
                         int* __restrict__ cursor, int* __restrict__ csr) {
    int base = blockIdx.x * 1024 + threadIdx.x;
    int d[4], s[4], pos[4];
#pragma unroll
    for (int i = 0; i < 4; ++i) {
        int e = base + i * 256;
        d[i] = (e < N_EDGES) ? dst[e] : -1;
        s[i] = (e < N_EDGES) ? src[e] : 0;
    }
#pragma unroll
    for (int i = 0; i < 4; ++i)
        pos[i] = (d[i] >= 0) ? atomicAdd(&cursor[d[i]], 1) : 0;
#pragma unroll
    for (int i = 0; i < 4; ++i)
        if (d[i] >= 0) csr[pos[i]] = s[i];
}

// ---------------- aggregation: ab = bf16( x + sum_{j->i} x_j ), x in bf16 ----------------
// 16 lanes/node, uint4 (8 bf16 = 16B) per lane, explicit 4-wide load phase -> 64B
// in flight per thread, fp32 accumulate.

__device__ __forceinline__ void acc8(float* a, uint4 v) {
    a[0] += bf2f(v.x & 0xffff); a[1] += bf2f(v.x >> 16);
    a[2] += bf2f(v.y & 0xffff); a[3] += bf2f(v.y >> 16);
    a[4] += bf2f(v.z & 0xffff); a[5] += bf2f(v.z >> 16);
    a[6] += bf2f(v.w & 0xffff); a[7] += bf2f(v.w >> 16);
}

__global__ void agg_kernel(const u16* __restrict__ xb, const int* __restrict__ csr,
                           const int* __restrict__ offsets, u16* __restrict__ ab) {
    int t = blockIdx.x * blockDim.x + threadIdx.x;
    int node = t >> 4;
    if (node >= N_NODES) return;
    int lane = t & 15;
    const uint4* xp = (const uint4*)(xb + lane * 8);   // advance: 16 uint4 per row
    float a[8] = {0, 0, 0, 0, 0, 0, 0, 0};
    acc8(a, xp[(size_t)node * 16]);
    int s = offsets[node], e = offsets[node + 1];
    int p = s;
    for (; p + 4 <= e; p += 4) {
        int j0 = csr[p], j1 = csr[p + 1], j2 = csr[p + 2], j3 = csr[p + 3];
        uint4 v0 = xp[(size_t)j0 * 16];
        uint4 v1 = xp[(size_t)j1 * 16];
        uint4 v2 = xp[(size_t)j2 * 16];
        uint4 v3 = xp[(size_t)j3 * 16];
        acc8(a, v0); acc8(a, v1); acc8(a, v2); acc8(a, v3);
    }
    for (; p < e; ++p)
        acc8(a, xp[(size_t)csr[p] * 16]);
    uint4 o;
    o.x = (u32)f2bf(a[0]) | ((u32)f2bf(a[1]) << 16);
    o.y = (u32)f2bf(a[2]) | ((u32)f2bf(a[3]) << 16);
    o.z = (u32)f2bf(a[4]) | ((u32)f2bf(a[5]) << 16);
    o.w = (u32)f2bf(a[6]) | ((u32)f2bf(a[7]) << 16);
    *(uint4*)&ab[(size_t)node * D + lane * 8] = o;
}

// ---------------- MFMA GEMM common geometry ----------------
// 256 thr = 4 waves, BM=128, N=128, K=128. Wave (wid): rows (wid>>1)*64, cols (wid&1)*64.
// Per wave: 4x4 tiles of 16x16, K in 4 steps of 32. LDS [row][k] bf16, 256B rows,
// XOR-swizzle byte ^= ((row&15)<<4) -> conflict-free ds_read_b128 fragments.

// GEMM1: H = leaky(A@W1 + b1) written bf16 IN PLACE over A; fused BN column stats.
__global__ __launch_bounds__(256, 2)
void gemm1_mfma(u16* __restrict__ AB, const u16* __restrict__ Wt,
                const float* __restrict__ bias,
                float* __restrict__ colsum, float* __restrict__ colsq) {
    __shared__ u16 As[128 * 128];
    __shared__ u16 Ws[128 * 128];
    __shared__ float csumL[D], csqL[D];
    int tid = threadIdx.x;
    int row0 = blockIdx.x * 128;

    if (tid < D) { csumL[tid] = 0.f; csqL[tid] = 0.f; }
    const uint4* Wg = (const uint4*)Wt;
#pragma unroll
    for (int i = 0; i < 8; ++i) {
        int q = i * 256 + tid;
        int m = q >> 4, kc = q & 15;
        uint4 wv = Wg[q];
        *(uint4*)((char*)Ws + m * 256 + ((kc * 16) ^ ((m & 15) << 4))) = wv;
        uint4 av = make_uint4(0, 0, 0, 0);
        int gm = row0 + m;
        if (gm < N_NODES) av = *(const uint4*)&AB[(size_t)gm * D + kc * 8];
        *(uint4*)((char*)As + m * 256 + ((kc * 16) ^ ((m & 15) << 4))) = av;
    }
    __syncthreads();

    int lane = tid & 63;
    int wid = tid >> 6;
    int mbase = (wid >> 1) * 64, nbase = (wid & 1) * 64;
    int lr = lane & 15, kg = lane >> 4;
    f32x4 acc[4][4];
#pragma unroll
    for (int mt = 0; mt < 4; ++mt)
#pragma unroll
        for (int nt = 0; nt < 4; ++nt) acc[mt][nt] = (f32x4)0.0f;

    const char* Ap = (const char*)As;
    const char* Wp = (const char*)Ws;
#pragma unroll
    for (int ks = 0; ks < 4; ++ks) {
        int kb2 = ks * 64 + kg * 16;
        short8 af[4], bfr[4];
#pragma unroll
        for (int t = 0; t < 4; ++t) {
            int m = mbase + t * 16 + lr;
            af[t] = *(const short8*)(Ap + m * 256 + (kb2 ^ ((m & 15) << 4)));
            int n = nbase + t * 16 + lr;
            bfr[t] = *(const short8*)(Wp + n * 256 + (kb2 ^ ((n & 15) << 4)));
        }
#pragma unroll
        for (int mt = 0; mt < 4; ++mt)
#pragma unroll
            for (int nt = 0; nt < 4; ++nt)
                acc[mt][nt] = __builtin_amdgcn_mfma_f32_16x16x32_bf16(af[mt], bfr[nt], acc[mt][nt], 0, 0, 0);
    }

    float bv[4], ls[4] = {0, 0, 0, 0}, lq[4] = {0, 0, 0, 0};
#pragma unroll
    for (int nt = 0; nt < 4; ++nt) bv[nt] = bias[nbase + nt * 16 + lr];
#pragma unroll
    for (int mt = 0; mt < 4; ++mt) {
#pragma unroll
        for (int r = 0; r < 4; ++r) {
            int gm = row0 + mbase + mt * 16 + kg * 4 + r;
            if (gm < N_NODES) {
#pragma unroll
                for (int nt = 0; nt < 4; ++nt) {
                    float z = acc[mt][nt][r] + bv[nt];
                    z = (z >= 0.f) ? z : 0.2f * z;
                    AB[(size_t)gm * D + nbase + nt * 16 + lr] = f2bf(z);
                    ls[nt] += z; lq[nt] += z * z;
                }
            }
        }
    }
#pragma unroll
    for (int nt = 0; nt < 4; ++nt) {
        ls[nt] += __shfl_down(ls[nt], 32); ls[nt] += __shfl_down(ls[nt], 16);
        lq[nt] += __shfl_down(lq[nt], 32); lq[nt] += __shfl_down(lq[nt], 16);
    }
    if (lane < 16) {
#pragma unroll
        for (int nt = 0; nt < 4; ++nt) {
            atomicAdd(&csumL[nbase + nt * 16 + lane], ls[nt]);
            atomicAdd(&csqL[nbase + nt * 16 + lane], lq[nt]);
        }
    }
    __syncthreads();
    if (tid < D) {
        atomicAdd(&colsum[tid], csumL[tid]);
        atomicAdd(&colsq[tid], csqL[tid]);
    }
}

// GEMM2: x = leaky(BN(H)@W2 + b2) + xres; writes fp32 x + bf16 copy.
__global__ __launch_bounds__(256, 2)
void gemm2_mfma(const u16* __restrict__ HB, const u16* __restrict__ Wt,
                const float* __restrict__ bias, const float* __restrict__ scalev,
                const float* __restrict__ shiftv, const float* __restrict__ xres,
                float* __restrict__ xout, u16* __restrict__ xbout) {
    __shared__ u16 As[128 * 128];
    __shared__ u16 Ws[128 * 128];
    int tid = threadIdx.x;
    int row0 = blockIdx.x * 128;

    const uint4* Wg = (const uint4*)Wt;
#pragma unroll
    for (int i = 0; i < 8; ++i) {
        int q = i * 256 + tid;
        int m = q >> 4, kc = q & 15;
        uint4 wv = Wg[q];
        *(uint4*)((char*)Ws + m * 256 + ((kc * 16) ^ ((m & 15) << 4))) = wv;
        uint4 av = make_uint4(0, 0, 0, 0);
        int gm = row0 + m;
        if (gm < N_NODES) {
            uint4 h = *(const uint4*)&HB[(size_t)gm * D + kc * 8];
            float4 s0 = *(const float4*)&scalev[kc * 8];
            float4 s1 = *(const float4*)&scalev[kc * 8 + 4];
            float4 t0 = *(const float4*)&shiftv[kc * 8];
            float4 t1 = *(const float4*)&shiftv[kc * 8 + 4];
            float f0 = bf2f(h.x & 0xffff) * s0.x + t0.x;
            float f1 = bf2f(h.x >> 16)    * s0.y + t0.y;
            float f2 = bf2f(h.y & 0xffff) * s0.z + t0.z;
            float f3 = bf2f(h.y >> 16)    * s0.w + t0.w;
            float f4 = bf2f(h.z & 0xffff) * s1.x + t1.x;
            float f5 = bf2f(h.z >> 16)    * s1.y + t1.y;
            float f6 = bf2f(h.w & 0xffff) * s1.z + t1.z;
            float f7 = bf2f(h.w >> 16)    * s1.w + t1.w;
            av.x = (u32)f2bf(f0) | ((u32)f2bf(f1) << 16);
            av.y = (u32)f2bf(f2) | ((u32)f2bf(f3) << 16);
            av.z = (u32)f2bf(f4) | ((u32)f2bf(f5) << 16);
            av.w = (u32)f2bf(f6) | ((u32)f2bf(f7) << 16);
        }
        *(uint4*)((char*)As + m * 256 + ((kc * 16) ^ ((m & 15) << 4))) = av;
    }
    __syncthreads();

    int lane = tid & 63;
    int wid = tid >> 6;
    int mbase = (wid >> 1) * 64, nbase = (wid & 1) * 64;
    int lr = lane & 15, kg = lane >> 4;
    f32x4 acc[4][4];
#pragma unroll
    for (int mt = 0; mt < 4; ++mt)
#pragma unroll
        for (int nt = 0; nt < 4; ++nt) acc[mt][nt] = (f32x4)0.0f;

    const char* Ap = (const char*)As;
    const char* Wp = (const char*)Ws;
#pragma unroll
    for (int ks = 0; ks < 4; ++ks) {
        int kb2 = ks * 64 + kg * 16;
        short8 af[4], bfr[4];
#pragma unroll
        for (int t = 0; t < 4; ++t) {
            int m = mbase + t * 16 + lr;
            af[t] = *(const short8*)(Ap + m * 256 + (kb2 ^ ((m & 15) << 4)));
            int n = nbase + t * 16 + lr;
            bfr[t] = *(const short8*)(Wp + n * 256 + (kb2 ^ ((n & 15) << 4)));
        }
#pragma unroll
        for (int mt = 0; mt < 4; ++mt)
#pragma unroll
            for (int nt = 0; nt < 4; ++nt)
                acc[mt][nt] = __builtin_amdgcn_mfma_f32_16x16x32_bf16(af[mt], bfr[nt], acc[mt][nt], 0, 0, 0);
    }

    float bv[4];
#pragma unroll
    for (int nt = 0; nt < 4; ++nt) bv[nt] = bias[nbase + nt * 16 + lr];
#pragma unroll
    for (int mt = 0; mt < 4; ++mt) {
#pragma unroll
        for (int r = 0; r < 4; ++r) {
            int gm = row0 + mbase + mt * 16 + kg * 4 + r;
            if (gm < N_NODES) {
#pragma unroll
                for (int nt = 0; nt < 4; ++nt) {
                    int gn = nbase + nt * 16 + lr;
                    float z = acc[mt][nt][r] + bv[nt];
                    z = (z >= 0.f) ? z : 0.2f * z;
                    float o = z + xres[(size_t)gm * D + gn];
                    xout[(size_t)gm * D + gn] = o;
                    xbout[(size_t)gm * D + gn] = f2bf(o);
                }
            }
        }
    }
}

// ---------------- BN finalize ----------------

__global__ void bn_fin(const float* __restrict__ colsum, const float* __restrict__ colsq,
                       const float* __restrict__ g, const float* __restrict__ bt,
                       float* __restrict__ scale, float* __restrict__ shift, float inv_n) {
    int c = threadIdx.x;
    float m = colsum[c] * inv_n;
    float var = colsq[c] * inv_n - m * m;
    var = fmaxf(var, 0.f);
    float sc = g[c] * rsqrtf(var + EPS);
    scale[c] = sc;
    shift[c] = bt[c] - m * sc;
}

// ---------------- pooling + final BN + fc ----------------

__global__ void bounds_kernel(const int* __restrict__ batch, int* __restrict__ gs, int* __restrict__ ge) {
    for (int i = blockIdx.x * blockDim.x + threadIdx.x; i < N_NODES; i += gridDim.x * blockDim.x) {
        int b = batch[i];
        atomicMin(&gs[b], i);
        atomicMax(&ge[b], i + 1);
    }
}

__global__ void pool_kernel(const float* __restrict__ x, const int* __restrict__ gs,
                            const int* __restrict__ ge, float* __restrict__ pooled) {
    int g = blockIdx.x, f = threadIdx.x;
    int s = gs[g], e = ge[g];
    float a0 = 0.f, a1 = 0.f, a2 = 0.f, a3 = 0.f;
    int i = s;
    for (; i + 4 <= e; i += 4) {
        a0 += x[(size_t)i * D + f];
        a1 += x[(size_t)(i + 1) * D + f];
        a2 += x[(size_t)(i + 2) * D + f];
        a3 += x[(size_t)(i + 3) * D + f];
    }
    for (; i < e; ++i) a0 += x[(size_t)i * D + f];
    pooled[g * D + f] = (a0 + a1) + (a2 + a3);
}

__global__ void pooled_bn(const float* __restrict__ pooled, const float* __restrict__ g,
                          const float* __restrict__ b, float* __restrict__ pscale,
                          float* __restrict__ pshift) {
    int c = threadIdx.x;
    float s = 0.f, q = 0.f;
    for (int gi = 0; gi < N_GRAPHS; ++gi) {
        float v = pooled[gi * D + c];
        s += v; q += v * v;
    }
    float m = s / N_GRAPHS;
    float var = q / N_GRAPHS - m * m;
    var = fmaxf(var, 0.f);
    float sc = g[c] * rsqrtf(var + EPS);
    pscale[c] = sc;
    pshift[c] = b[c] - m * sc;
}

__global__ void out_kernel(const float* __restrict__ pooled, const float* __restrict__ pscale,
                           const float* __restrict__ pshift, const float* __restrict__ fcW,
                           const float* __restrict__ fcb, float* __restrict__ out) {
    int idx = blockIdx.x * blockDim.x + threadIdx.x;
    if (idx >= N_GRAPHS * LATENT) return;
    int g = idx >> 6, j = idx & 63;
    float acc = fcb[j];
    for (int c = 0; c < D; ++c) {
        float pv = pooled[g * D + c] * pscale[c] + pshift[c];
        acc += pv * fcW[c * LATENT + j];
    }
    out[idx] = acc;
}

// ---------------- launch ----------------

extern "C" void kernel_launch(void* const* d_in, const int* in_sizes, int n_in,
                              void* d_out, int out_size, void* d_ws, size_t ws_size,
                              hipStream_t stream) {
    const float* x_in = (const float*)d_in[0];
    const int* edges  = (const int*)d_in[1];
    const int* batch  = (const int*)d_in[2];
    const float* W1   = (const float*)d_in[3];
    const float* b1   = (const float*)d_in[4];
    const float* g1   = (const float*)d_in[5];
    const float* bt1  = (const float*)d_in[6];
    const float* W2   = (const float*)d_in[7];
    const float* b2   = (const float*)d_in[8];
    const float* bng  = (const float*)d_in[9];
    const float* bnb  = (const float*)d_in[10];
    const float* fcW  = (const float*)d_in[11];
    const float* fcb  = (const float*)d_in[12];
    float* out = (float*)d_out;
    const int* srcp = edges;
    const int* dstp = edges + N_EDGES;

    char* p = (char*)d_ws;
    auto alloc = [&](size_t bytes) -> char* {
        char* r = p;
        p += (bytes + 511) & ~(size_t)511;
        return r;
    };
    float* XF      = (float*)alloc((size_t)N_NODES * D * 4);   // fp32 residual stream x
    u16*   XB      = (u16*)alloc((size_t)N_NODES * D * 2);     // bf16 copy of x (gather input)
    u16*   AB      = (u16*)alloc((size_t)N_NODES * D * 2);     // agg out -> H (in place)
    int*   csr     = (int*)alloc((size_t)N_EDGES * 4);
    int*   deg     = (int*)alloc((size_t)N_NODES * 4);
    int*   offsets = (int*)alloc((size_t)(N_NODES + 1) * 4);
    int*   cursor  = (int*)alloc((size_t)N_NODES * 4);
    int*   bsum    = (int*)alloc((size_t)NB * 4);
    int*   boff    = (int*)alloc((size_t)NB * 4);
    u16*   Wtb     = (u16*)alloc((size_t)6 * D * D * 2);       // bf16 transposed weights
    float* colsum  = (float*)alloc(D * 4);
    float* colsq   = (float*)alloc(D * 4);
    float* scalev  = (float*)alloc(D * 4);
    float* shiftv  = (float*)alloc(D * 4);
    int*   gs      = (int*)alloc(N_GRAPHS * 4);
    int*   ge      = (int*)alloc(N_GRAPHS * 4);
    float* pooled  = (float*)alloc((size_t)N_GRAPHS * D * 4);
    float* pscale  = (float*)alloc(D * 4);
    float* pshift  = (float*)alloc(D * 4);

    conv_w<<<6, 256, 0, stream>>>(W1, W2, Wtb);
    conv_x<<<(N_NODES * D / 4 + 255) / 256, 256, 0, stream>>>(x_in, XB);

    hipMemsetAsync(deg, 0, (size_t)N_NODES * 4, stream);
    const int EDGE_GRID4 = (N_EDGES + 1023) / 1024;  // 1563
    hist_kernel<<<EDGE_GRID4, 256, 0, stream>>>(dstp, deg);
    scan_block_sum<<<NB, 256, 0, stream>>>(deg, bsum);
    scan_top<<<1, 512, 0, stream>>>(bsum, boff);
    scan_apply<<<NB, 256, 0, stream>>>(deg, boff, offsets, cursor);
    csr_fill<<<EDGE_GRID4, 256, 0, stream>>>(srcp, dstp, cursor, csr);

    const int GEMM_GRID = (N_NODES + 127) / 128;      // 782
    const int AGG_GRID = (N_NODES * 16 + 255) / 256;  // 6250
    for (int l = 0; l < 3; ++l) {
        agg_kernel<<<AGG_GRID, 256, 0, stream>>>(XB, csr, offsets, AB);
        hipMemsetAsync(colsum, 0, D * 4, stream);
        hipMemsetAsync(colsq, 0, D * 4, stream);
        gemm1_mfma<<<GEMM_GRID, 256, 0, stream>>>(AB, Wtb + (size_t)l * D * D, b1 + l * D,
                                                  colsum, colsq);
        bn_fin<<<1, D, 0, stream>>>(colsum, colsq, g1 + l * D, bt1 + l * D, scalev, shiftv,
                                    1.0f / N_NODES);
        const float* xr = (l == 0) ? x_in : XF;
        gemm2_mfma<<<GEMM_GRID, 256, 0, stream>>>(AB, Wtb + (size_t)(3 + l) * D * D, b2 + l * D,
                                                  scalev, shiftv, xr, XF, XB);
    }

    hipMemsetAsync(gs, 0x7f, N_GRAPHS * 4, stream);
    hipMemsetAsync(ge, 0, N_GRAPHS * 4, stream);
    bounds_kernel<<<256, 256, 0, stream>>>(batch, gs, ge);
    pool_kernel<<<N_GRAPHS, D, 0, stream>>>(XF, gs, ge, pooled);
    pooled_bn<<<1, D, 0, stream>>>(pooled, bng, bnb, pscale, pshift);
    out_kernel<<<(N_GRAPHS * LATENT + 255) / 256, 256, 0, stream>>>(pooled, pscale, pshift,
                                                                    fcW, fcb, out);
}

// Round 5
// 609.541 us; speedup vs baseline: 2.7180x; 1.1320x over previous
//
#include <hip/hip_runtime.h>

#define N_NODES 100000
#define N_EDGES 1600000
#define N_GRAPHS 1000
#define D 128
#define LATENT 64
#define EPS 1e-5f
#define NB ((N_NODES + 255) / 256)   // 391
#define NBUCK 196                    // buckets of 512 nodes: bucket = dst >> 9
#define BSH 9

typedef unsigned short u16;
typedef unsigned int u32;
typedef __attribute__((ext_vector_type(8))) short short8;   // 8 bf16 = 4 VGPR (MFMA A/B frag)
typedef __attribute__((ext_vector_type(4))) float f32x4;    // MFMA C/D frag

__device__ __forceinline__ float bf2f(u32 u) {
    union { u32 i; float f; } c; c.i = u << 16; return c.f;
}
__device__ __forceinline__ u16 f2bf(float f) {
    union { float f; u32 u; } c; c.f = f;
    u32 u = c.u;
    return (u16)((u + 0x7fffu + ((u >> 16) & 1u)) >> 16);   // RNE
}

// ---------------- weight convert: W[k][n] fp32 -> Wt[n][k] bf16 (6 matrices) ----------------

__global__ void conv_w(const float* __restrict__ W1, const float* __restrict__ W2,
                       u16* __restrict__ Wt) {
    int b = blockIdx.x;
    const float* src = (b < 3) ? (W1 + (size_t)b * D * D) : (W2 + (size_t)(b - 3) * D * D);
    u16* dst = Wt + (size_t)b * D * D;
    for (int i = threadIdx.x; i < D * D; i += blockDim.x) {
        int k = i >> 7, n = i & 127;
        dst[n * D + k] = f2bf(src[i]);
    }
}

// ---------------- x fp32 -> bf16 ----------------

__global__ void conv_x(const float* __restrict__ x, u16* __restrict__ xb) {
    int idx = blockIdx.x * blockDim.x + threadIdx.x;
    if (idx >= N_NODES * D / 4) return;
    float4 v = *(const float4*)&x[(size_t)idx * 4];
    u32 lo = (u32)f2bf(v.x) | ((u32)f2bf(v.y) << 16);
    u32 hi = (u32)f2bf(v.z) | ((u32)f2bf(v.w) << 16);
    *(uint2*)&xb[(size_t)idx * 4] = make_uint2(lo, hi);
}

// ---------------- bucketed CSR build ----------------
// Phase A: counting-sort edges into 196 buckets of 512 dst-nodes (LDS-staged,
// coalesced flushes). Phase B: per-bucket LDS histogram (no global atomics).
// Phase C: per-bucket CSR fill with LDS cursors; writes confined to ~32KB window.

__global__ void bucket_hist(const int* __restrict__ dst, int* __restrict__ bhist) {
    __shared__ int cnt[256];
    int t = threadIdx.x;
    cnt[t] = 0;
    __syncthreads();
    int base = blockIdx.x * 4096 + t * 16;
#pragma unroll
    for (int i = 0; i < 16; ++i) {
        int e = base + i;
        if (e < N_EDGES) atomicAdd(&cnt[dst[e] >> BSH], 1);
    }
    __syncthreads();
    if (t < NBUCK && cnt[t] > 0) atomicAdd(&bhist[t], cnt[t]);
}

__global__ void bucket_scan(const int* __restrict__ bhist, int* __restrict__ bstart,
                            int* __restrict__ gbcur) {
    __shared__ int s[256];
    int t = threadIdx.x;
    int v = (t < NBUCK) ? bhist[t] : 0;
    s[t] = v;
    __syncthreads();
    for (int off = 1; off < 256; off <<= 1) {
        int a = (t >= off) ? s[t - off] : 0;
        __syncthreads();
        s[t] += a;
        __syncthreads();
    }
    if (t < NBUCK) { int ex = s[t] - v; bstart[t] = ex; gbcur[t] = ex; }
    if (t == NBUCK - 1) bstart[NBUCK] = s[t];
}

__global__ __launch_bounds__(256)
void bucket_scatter(const int* __restrict__ src, const int* __restrict__ dst,
                    int* __restrict__ gbcur, int* __restrict__ ebs, int* __restrict__ ebd) {
    __shared__ int cnt[256], loff[256], basev[256], scn[256];
    __shared__ int psrc[4096], pdst[4096];
    __shared__ unsigned char pbkt[4096];
    int t = threadIdx.x;
    cnt[t] = 0;
    __syncthreads();
    int ebase = blockIdx.x * 4096;
    int d[16], sv[16], b[16], r[16];
#pragma unroll
    for (int i = 0; i < 16; ++i) {
        int e = ebase + t * 16 + i;
        bool ok = e < N_EDGES;
        d[i] = ok ? dst[e] : 0;
        sv[i] = ok ? src[e] : 0;
        b[i] = ok ? (d[i] >> BSH) : -1;
    }
#pragma unroll
    for (int i = 0; i < 16; ++i)
        r[i] = (b[i] >= 0) ? atomicAdd(&cnt[b[i]], 1) : 0;
    __syncthreads();
    int c = cnt[t];
    scn[t] = c;
    __syncthreads();
    for (int off = 1; off < 256; off <<= 1) {
        int a = (t >= off) ? scn[t - off] : 0;
        __syncthreads();
        scn[t] += a;
        __syncthreads();
    }
    loff[t] = scn[t] - c;
    if (c > 0) basev[t] = atomicAdd(&gbcur[t], c);
    __syncthreads();
#pragma unroll
    for (int i = 0; i < 16; ++i) {
        if (b[i] >= 0) {
            int p = loff[b[i]] + r[i];
            psrc[p] = sv[i];
            pdst[p] = d[i];
            pbkt[p] = (unsigned char)b[i];
        }
    }
    __syncthreads();
    int total = min(4096, N_EDGES - ebase);
    for (int i = t; i < total; i += 256) {
        int bb = pbkt[i];
        int g = basev[bb] + (i - loff[bb]);
        ebs[g] = psrc[i];
        ebd[g] = pdst[i];
    }
}

__global__ void hist_local(const int* __restrict__ ebd, const int* __restrict__ bstart,
                           int* __restrict__ deg) {
    __shared__ int h[512];
    int b = blockIdx.x, t = threadIdx.x;
    int nbase = b << BSH;
    h[t] = 0; h[t + 256] = 0;
    __syncthreads();
    int e0 = bstart[b], e1 = bstart[b + 1];
    for (int e = e0 + t; e < e1; e += 256)
        atomicAdd(&h[ebd[e] - nbase], 1);
    __syncthreads();
    int nlen = min(512, N_NODES - nbase);
    if (t < nlen) deg[nbase + t] = h[t];
    if (t + 256 < nlen) deg[nbase + t + 256] = h[t + 256];
}

__global__ void scan_block_sum(const int* __restrict__ deg, int* __restrict__ bsum) {
    __shared__ int s[256];
    int t = threadIdx.x;
    int i = blockIdx.x * 256 + t;
    s[t] = (i < N_NODES) ? deg[i] : 0;
    __syncthreads();
    for (int off = 128; off > 0; off >>= 1) {
        if (t < off) s[t] += s[t + off];
        __syncthreads();
    }
    if (t == 0) bsum[blockIdx.x] = s[0];
}

__global__ void scan_top(const int* __restrict__ bsum, int* __restrict__ boff) {
    __shared__ int s[512];
    int t = threadIdx.x;
    int v = (t < NB) ? bsum[t] : 0;
    s[t] = v;
    __syncthreads();
    for (int off = 1; off < 512; off <<= 1) {
        int add = (t >= off) ? s[t - off] : 0;
        __syncthreads();
        s[t] += add;
        __syncthreads();
    }
    if (t < NB) boff[t] = s[t] - v;
}

__global__ void scan_apply(const int* __restrict__ deg, const int* __restrict__ boff,
                           int* __restrict__ offsets) {
    __shared__ int s[256];
    int t = threadIdx.x;
    int i = blockIdx.x * 256 + t;
    int v = (i < N_NODES) ? deg[i] : 0;
    s[t] = v;
    __syncthreads();
    for (int off = 1; off < 256; off <<= 1) {
        int add = (t >= off) ? s[t - off] : 0;
        __syncthreads();
        s[t] += add;
        __syncthreads();
    }
    int base = boff[blockIdx.x];
    if (i < N_NODES) offsets[i] = base + s[t] - v;
    if (i == N_NODES - 1) offsets[N_NODES] = base + s[t];
}

__global__ void csr_fill_local(const int* __restrict__ ebs, const int* __restrict__ ebd,
                               const int* __restrict__ bstart, const int* __restrict__ offsets,
                               int* __restrict__ csr) {
    __shared__ int cur[512];
    int b = blockIdx.x, t = threadIdx.x;
    int nbase = b << BSH;
    int nlen = min(512, N_NODES - nbase);
    if (t < nlen) cur[t] = offsets[nbase + t];
    if (t + 256 < nlen) cur[t + 256] = offsets[nbase + t + 256];
    __syncthreads();
    int e0 = bstart[b], e1 = bstart[b + 1];
    for (int e = e0 + t; e < e1; e += 256) {
        int p = atomicAdd(&cur[ebd[e] - nbase], 1);
        csr[p] = ebs[e];
    }
}

// ---------------- aggregation: ab = bf16( x + sum_{j->i} x_j ), x in bf16 ----------------

__device__ __forceinline__ void acc8(float* a, uint4 v) {
    a[0] += bf2f(v.x & 0xffff); a[1] += bf2f(v.x >> 16);
    a[2] += bf2f(v.y & 0xffff); a[3] += bf2f(v.y >> 16);
    a[4] += bf2f(v.z & 0xffff); a[5] += bf2f(v.z >> 16);
    a[6] += bf2f(v.w & 0xffff); a[7] += bf2f(v.w >> 16);
}

__global__ void agg_kernel(const u16* __restrict__ xb, const int* __restrict__ csr,
                           const int* __restrict__ offsets, u16* __restrict__ ab) {
    int t = blockIdx.x * blockDim.x + threadIdx.x;
    int node = t >> 4;
    if (node >= N_NODES) return;
    int lane = t & 15;
    const uint4* xp = (const uint4*)(xb + lane * 8);   // advance: 16 uint4 per row
    float a[8] = {0, 0, 0, 0, 0, 0, 0, 0};
    acc8(a, xp[(size_t)node * 16]);
    int s = offsets[node], e = offsets[node + 1];
    int p = s;
    for (; p + 4 <= e; p += 4) {
        int j0 = csr[p], j1 = csr[p + 1], j2 = csr[p + 2], j3 = csr[p + 3];
        uint4 v0 = xp[(size_t)j0 * 16];
        uint4 v1 = xp[(size_t)j1 * 16];
        uint4 v2 = xp[(size_t)j2 * 16];
        uint4 v3 = xp[(size_t)j3 * 16];
        acc8(a, v0); acc8(a, v1); acc8(a, v2); acc8(a, v3);
    }
    for (; p < e; ++p)
        acc8(a, xp[(size_t)csr[p] * 16]);
    uint4 o;
    o.x = (u32)f2bf(a[0]) | ((u32)f2bf(a[1]) << 16);
    o.y = (u32)f2bf(a[2]) | ((u32)f2bf(a[3]) << 16);
    o.z = (u32)f2bf(a[4]) | ((u32)f2bf(a[5]) << 16);
    o.w = (u32)f2bf(a[6]) | ((u32)f2bf(a[7]) << 16);
    *(uint4*)&ab[(size_t)node * D + lane * 8] = o;
}

// ---------------- MFMA GEMM common geometry ----------------
// 256 thr = 4 waves, BM=128, N=128, K=128. Wave (wid): rows (wid>>1)*64, cols (wid&1)*64.
// Per wave: 4x4 tiles of 16x16, K in 4 steps of 32. LDS [row][k] bf16, 256B rows,
// XOR-swizzle byte ^= ((row&15)<<4) -> conflict-free ds_read_b128 fragments.

// GEMM1: H = leaky(A@W1 + b1) written bf16 IN PLACE over A; fused BN column stats.
__global__ __launch_bounds__(256, 2)
void gemm1_mfma(u16* __restrict__ AB, const u16* __restrict__ Wt,
                const float* __restrict__ bias,
                float* __restrict__ colsum, float* __restrict__ colsq) {
    __shared__ u16 As[128 * 128];
    __shared__ u16 Ws[128 * 128];
    __shared__ float csumL[D], csqL[D];
    int tid = threadIdx.x;
    int row0 = blockIdx.x * 128;

    if (tid < D) { csumL[tid] = 0.f; csqL[tid] = 0.f; }
    const uint4* Wg = (const uint4*)Wt;
#pragma unroll
    for (int i = 0; i < 8; ++i) {
        int q = i * 256 + tid;
        int m = q >> 4, kc = q & 15;
        uint4 wv = Wg[q];
        *(uint4*)((char*)Ws + m * 256 + ((kc * 16) ^ ((m & 15) << 4))) = wv;
        uint4 av = make_uint4(0, 0, 0, 0);
        int gm = row0 + m;
        if (gm < N_NODES) av = *(const uint4*)&AB[(size_t)gm * D + kc * 8];
        *(uint4*)((char*)As + m * 256 + ((kc * 16) ^ ((m & 15) << 4))) = av;
    }
    __syncthreads();

    int lane = tid & 63;
    int wid = tid >> 6;
    int mbase = (wid >> 1) * 64, nbase = (wid & 1) * 64;
    int lr = lane & 15, kg = lane >> 4;
    f32x4 acc[4][4];
#pragma unroll
    for (int mt = 0; mt < 4; ++mt)
#pragma unroll
        for (int nt = 0; nt < 4; ++nt) acc[mt][nt] = (f32x4)0.0f;

    const char* Ap = (const char*)As;
    const char* Wp = (const char*)Ws;
#pragma unroll
    for (int ks = 0; ks < 4; ++ks) {
        int kb2 = ks * 64 + kg * 16;
        short8 af[4], bfr[4];
#pragma unroll
        for (int t = 0; t < 4; ++t) {
            int m = mbase + t * 16 + lr;
            af[t] = *(const short8*)(Ap + m * 256 + (kb2 ^ ((m & 15) << 4)));
            int n = nbase + t * 16 + lr;
            bfr[t] = *(const short8*)(Wp + n * 256 + (kb2 ^ ((n & 15) << 4)));
        }
#pragma unroll
        for (int mt = 0; mt < 4; ++mt)
#pragma unroll
            for (int nt = 0; nt < 4; ++nt)
                acc[mt][nt] = __builtin_amdgcn_mfma_f32_16x16x32_bf16(af[mt], bfr[nt], acc[mt][nt], 0, 0, 0);
    }

    float bv[4], ls[4] = {0, 0, 0, 0}, lq[4] = {0, 0, 0, 0};
#pragma unroll
    for (int nt = 0; nt < 4; ++nt) bv[nt] = bias[nbase + nt * 16 + lr];
#pragma unroll
    for (int mt = 0; mt < 4; ++mt) {
#pragma unroll
        for (int r = 0; r < 4; ++r) {
            int gm = row0 + mbase + mt * 16 + kg * 4 + r;
            if (gm < N_NODES) {
#pragma unroll
                for (int nt = 0; nt < 4; ++nt) {
                    float z = acc[mt][nt][r] + bv[nt];
                    z = (z >= 0.f) ? z : 0.2f * z;
                    AB[(size_t)gm * D + nbase + nt * 16 + lr] = f2bf(z);
                    ls[nt] += z; lq[nt] += z * z;
                }
            }
        }
    }
#pragma unroll
    for (int nt = 0; nt < 4; ++nt) {
        ls[nt] += __shfl_down(ls[nt], 32); ls[nt] += __shfl_down(ls[nt], 16);
        lq[nt] += __shfl_down(lq[nt], 32); lq[nt] += __shfl_down(lq[nt], 16);
    }
    if (lane < 16) {
#pragma unroll
        for (int nt = 0; nt < 4; ++nt) {
            atomicAdd(&csumL[nbase + nt * 16 + lane], ls[nt]);
            atomicAdd(&csqL[nbase + nt * 16 + lane], lq[nt]);
        }
    }
    __syncthreads();
    if (tid < D) {
        atomicAdd(&colsum[tid], csumL[tid]);
        atomicAdd(&colsq[tid], csqL[tid]);
    }
}

// GEMM2: x = leaky(BN(H)@W2 + b2) + xres; writes fp32 x + bf16 copy.
__global__ __launch_bounds__(256, 2)
void gemm2_mfma(const u16* __restrict__ HB, const u16* __restrict__ Wt,
                const float* __restrict__ bias, const float* __restrict__ scalev,
                const float* __restrict__ shiftv, const float* __restrict__ xres,
                float* __restrict__ xout, u16* __restrict__ xbout) {
    __shared__ u16 As[128 * 128];
    __shared__ u16 Ws[128 * 128];
    int tid = threadIdx.x;
    int row0 = blockIdx.x * 128;

    const uint4* Wg = (const uint4*)Wt;
#pragma unroll
    for (int i = 0; i < 8; ++i) {
        int q = i * 256 + tid;
        int m = q >> 4, kc = q & 15;
        uint4 wv = Wg[q];
        *(uint4*)((char*)Ws + m * 256 + ((kc * 16) ^ ((m & 15) << 4))) = wv;
        uint4 av = make_uint4(0, 0, 0, 0);
        int gm = row0 + m;
        if (gm < N_NODES) {
            uint4 h = *(const uint4*)&HB[(size_t)gm * D + kc * 8];
            float4 s0 = *(const float4*)&scalev[kc * 8];
            float4 s1 = *(const float4*)&scalev[kc * 8 + 4];
            float4 t0 = *(const float4*)&shiftv[kc * 8];
            float4 t1 = *(const float4*)&shiftv[kc * 8 + 4];
            float f0 = bf2f(h.x & 0xffff) * s0.x + t0.x;
            float f1 = bf2f(h.x >> 16)    * s0.y + t0.y;
            float f2 = bf2f(h.y & 0xffff) * s0.z + t0.z;
            float f3 = bf2f(h.y >> 16)    * s0.w + t0.w;
            float f4 = bf2f(h.z & 0xffff) * s1.x + t1.x;
            float f5 = bf2f(h.z >> 16)    * s1.y + t1.y;
            float f6 = bf2f(h.w & 0xffff) * s1.z + t1.z;
            float f7 = bf2f(h.w >> 16)    * s1.w + t1.w;
            av.x = (u32)f2bf(f0) | ((u32)f2bf(f1) << 16);
            av.y = (u32)f2bf(f2) | ((u32)f2bf(f3) << 16);
            av.z = (u32)f2bf(f4) | ((u32)f2bf(f5) << 16);
            av.w = (u32)f2bf(f6) | ((u32)f2bf(f7) << 16);
        }
        *(uint4*)((char*)As + m * 256 + ((kc * 16) ^ ((m & 15) << 4))) = av;
    }
    __syncthreads();

    int lane = tid & 63;
    int wid = tid >> 6;
    int mbase = (wid >> 1) * 64, nbase = (wid & 1) * 64;
    int lr = lane & 15, kg = lane >> 4;
    f32x4 acc[4][4];
#pragma unroll
    for (int mt = 0; mt < 4; ++mt)
#pragma unroll
        for (int nt = 0; nt < 4; ++nt) acc[mt][nt] = (f32x4)0.0f;

    const char* Ap = (const char*)As;
    const char* Wp = (const char*)Ws;
#pragma unroll
    for (int ks = 0; ks < 4; ++ks) {
        int kb2 = ks * 64 + kg * 16;
        short8 af[4], bfr[4];
#pragma unroll
        for (int t = 0; t < 4; ++t) {
            int m = mbase + t * 16 + lr;
            af[t] = *(const short8*)(Ap + m * 256 + (kb2 ^ ((m & 15) << 4)));
            int n = nbase + t * 16 + lr;
            bfr[t] = *(const short8*)(Wp + n * 256 + (kb2 ^ ((n & 15) << 4)));
        }
#pragma unroll
        for (int mt = 0; mt < 4; ++mt)
#pragma unroll
            for (int nt = 0; nt < 4; ++nt)
                acc[mt][nt] = __builtin_amdgcn_mfma_f32_16x16x32_bf16(af[mt], bfr[nt], acc[mt][nt], 0, 0, 0);
    }

    float bv[4];
#pragma unroll
    for (int nt = 0; nt < 4; ++nt) bv[nt] = bias[nbase + nt * 16 + lr];
#pragma unroll
    for (int mt = 0; mt < 4; ++mt) {
#pragma unroll
        for (int r = 0; r < 4; ++r) {
            int gm = row0 + mbase + mt * 16 + kg * 4 + r;
            if (gm < N_NODES) {
#pragma unroll
                for (int nt = 0; nt < 4; ++nt) {
                    int gn = nbase + nt * 16 + lr;
                    float z = acc[mt][nt][r] + bv[nt];
                    z = (z >= 0.f) ? z : 0.2f * z;
                    float o = z + xres[(size_t)gm * D + gn];
                    xout[(size_t)gm * D + gn] = o;
                    xbout[(size_t)gm * D + gn] = f2bf(o);
                }
            }
        }
    }
}

// ---------------- BN finalize ----------------

__global__ void bn_fin(const float* __restrict__ colsum, const float* __restrict__ colsq,
                       const float* __restrict__ g, const float* __restrict__ bt,
                       float* __restrict__ scale, float* __restrict__ shift, float inv_n) {
    int c = threadIdx.x;
    float m = colsum[c] * inv_n;
    float var = colsq[c] * inv_n - m * m;
    var = fmaxf(var, 0.f);
    float sc = g[c] * rsqrtf(var + EPS);
    scale[c] = sc;
    shift[c] = bt[c] - m * sc;
}

// ---------------- pooling + final BN + fc ----------------

__global__ void bounds_kernel(const int* __restrict__ batch, int* __restrict__ gs, int* __restrict__ ge) {
    for (int i = blockIdx.x * blockDim.x + threadIdx.x; i < N_NODES; i += gridDim.x * blockDim.x) {
        int b = batch[i];
        atomicMin(&gs[b], i);
        atomicMax(&ge[b], i + 1);
    }
}

__global__ void pool_kernel(const float* __restrict__ x, const int* __restrict__ gs,
                            const int* __restrict__ ge, float* __restrict__ pooled) {
    int g = blockIdx.x, f = threadIdx.x;
    int s = gs[g], e = ge[g];
    float a0 = 0.f, a1 = 0.f, a2 = 0.f, a3 = 0.f;
    int i = s;
    for (; i + 4 <= e; i += 4) {
        a0 += x[(size_t)i * D + f];
        a1 += x[(size_t)(i + 1) * D + f];
        a2 += x[(size_t)(i + 2) * D + f];
        a3 += x[(size_t)(i + 3) * D + f];
    }
    for (; i < e; ++i) a0 += x[(size_t)i * D + f];
    pooled[g * D + f] = (a0 + a1) + (a2 + a3);
}

__global__ void pooled_bn(const float* __restrict__ pooled, const float* __restrict__ g,
                          const float* __restrict__ b, float* __restrict__ pscale,
                          float* __restrict__ pshift) {
    int c = threadIdx.x;
    float s = 0.f, q = 0.f;
    for (int gi = 0; gi < N_GRAPHS; ++gi) {
        float v = pooled[gi * D + c];
        s += v; q += v * v;
    }
    float m = s / N_GRAPHS;
    float var = q / N_GRAPHS - m * m;
    var = fmaxf(var, 0.f);
    float sc = g[c] * rsqrtf(var + EPS);
    pscale[c] = sc;
    pshift[c] = b[c] - m * sc;
}

__global__ void out_kernel(const float* __restrict__ pooled, const float* __restrict__ pscale,
                           const float* __restrict__ pshift, const float* __restrict__ fcW,
                           const float* __restrict__ fcb, float* __restrict__ out) {
    int idx = blockIdx.x * blockDim.x + threadIdx.x;
    if (idx >= N_GRAPHS * LATENT) return;
    int g = idx >> 6, j = idx & 63;
    float acc = fcb[j];
    for (int c = 0; c < D; ++c) {
        float pv = pooled[g * D + c] * pscale[c] + pshift[c];
        acc += pv * fcW[c * LATENT + j];
    }
    out[idx] = acc;
}

// ---------------- launch ----------------

extern "C" void kernel_launch(void* const* d_in, const int* in_sizes, int n_in,
                              void* d_out, int out_size, void* d_ws, size_t ws_size,
                              hipStream_t stream) {
    const float* x_in = (const float*)d_in[0];
    const int* edges  = (const int*)d_in[1];
    const int* batch  = (const int*)d_in[2];
    const float* W1   = (const float*)d_in[3];
    const float* b1   = (const float*)d_in[4];
    const float* g1   = (const float*)d_in[5];
    const float* bt1  = (const float*)d_in[6];
    const float* W2   = (const float*)d_in[7];
    const float* b2   = (const float*)d_in[8];
    const float* bng  = (const float*)d_in[9];
    const float* bnb  = (const float*)d_in[10];
    const float* fcW  = (const float*)d_in[11];
    const float* fcb  = (const float*)d_in[12];
    float* out = (float*)d_out;
    const int* srcp = edges;
    const int* dstp = edges + N_EDGES;

    char* p = (char*)d_ws;
    auto alloc = [&](size_t bytes) -> char* {
        char* r = p;
        p += (bytes + 511) & ~(size_t)511;
        return r;
    };
    float* XF      = (float*)alloc((size_t)N_NODES * D * 4);   // fp32 residual stream x
    u16*   XB      = (u16*)alloc((size_t)N_NODES * D * 2);     // bf16 copy of x (gather input)
    u16*   AB      = (u16*)alloc((size_t)N_NODES * D * 2);     // agg out -> H (in place)
    int*   csr     = (int*)alloc((size_t)N_EDGES * 4);
    int*   deg     = (int*)alloc((size_t)N_NODES * 4);
    int*   offsets = (int*)alloc((size_t)(N_NODES + 1) * 4);
    int*   bsum    = (int*)alloc((size_t)NB * 4);
    int*   boff    = (int*)alloc((size_t)NB * 4);
    int*   bhist   = (int*)alloc((size_t)NBUCK * 4);
    int*   bstart  = (int*)alloc((size_t)(NBUCK + 1) * 4);
    int*   gbcur   = (int*)alloc((size_t)NBUCK * 4);
    u16*   Wtb     = (u16*)alloc((size_t)6 * D * D * 2);       // bf16 transposed weights
    float* colsum  = (float*)alloc(D * 4);
    float* colsq   = (float*)alloc(D * 4);
    float* scalev  = (float*)alloc(D * 4);
    float* shiftv  = (float*)alloc(D * 4);
    int*   gs      = (int*)alloc(N_GRAPHS * 4);
    int*   ge      = (int*)alloc(N_GRAPHS * 4);
    float* pooled  = (float*)alloc((size_t)N_GRAPHS * D * 4);
    float* pscale  = (float*)alloc(D * 4);
    float* pshift  = (float*)alloc(D * 4);

    // bucketed edge pairs aliased into XF (XF first written by layer-0 gemm2,
    // strictly after CSR build -> stream-ordered, safe).
    int* ebs = (int*)XF;
    int* ebd = (int*)XF + 2 * 1024 * 1024;

    conv_w<<<6, 256, 0, stream>>>(W1, W2, Wtb);
    conv_x<<<(N_NODES * D / 4 + 255) / 256, 256, 0, stream>>>(x_in, XB);

    const int EGRID = (N_EDGES + 4095) / 4096;   // 391
    hipMemsetAsync(bhist, 0, NBUCK * 4, stream);
    bucket_hist<<<EGRID, 256, 0, stream>>>(dstp, bhist);
    bucket_scan<<<1, 256, 0, stream>>>(bhist, bstart, gbcur);
    bucket_scatter<<<EGRID, 256, 0, stream>>>(srcp, dstp, gbcur, ebs, ebd);
    hist_local<<<NBUCK, 256, 0, stream>>>(ebd, bstart, deg);
    scan_block_sum<<<NB, 256, 0, stream>>>(deg, bsum);
    scan_top<<<1, 512, 0, stream>>>(bsum, boff);
    scan_apply<<<NB, 256, 0, stream>>>(deg, boff, offsets);
    csr_fill_local<<<NBUCK, 256, 0, stream>>>(ebs, ebd, bstart, offsets, csr);

    const int GEMM_GRID = (N_NODES + 127) / 128;      // 782
    const int AGG_GRID = (N_NODES * 16 + 255) / 256;  // 6250
    for (int l = 0; l < 3; ++l) {
        agg_kernel<<<AGG_GRID, 256, 0, stream>>>(XB, csr, offsets, AB);
        hipMemsetAsync(colsum, 0, D * 4, stream);
        hipMemsetAsync(colsq, 0, D * 4, stream);
        gemm1_mfma<<<GEMM_GRID, 256, 0, stream>>>(AB, Wtb + (size_t)l * D * D, b1 + l * D,
                                                  colsum, colsq);
        bn_fin<<<1, D, 0, stream>>>(colsum, colsq, g1 + l * D, bt1 + l * D, scalev, shiftv,
                                    1.0f / N_NODES);
        const float* xr = (l == 0) ? x_in : XF;
        gemm2_mfma<<<GEMM_GRID, 256, 0, stream>>>(AB, Wtb + (size_t)(3 + l) * D * D, b2 + l * D,
                                                  scalev, shiftv, xr, XF, XB);
    }

    hipMemsetAsync(gs, 0x7f, N_GRAPHS * 4, stream);
    hipMemsetAsync(ge, 0, N_GRAPHS * 4, stream);
    bounds_kernel<<<256, 256, 0, stream>>>(batch, gs, ge);
    pool_kernel<<<N_GRAPHS, D, 0, stream>>>(XF, gs, ge, pooled);
    pooled_bn<<<1, D, 0, stream>>>(pooled, bng, bnb, pscale, pshift);
    out_kernel<<<(N_GRAPHS * LATENT + 255) / 256, 256, 0, stream>>>(pooled, pscale, pshift,
                                                                    fcW, fcb, out);
}